// Round 12
// baseline (347.367 us; speedup 1.0000x reference)
//
#include <hip/hip_runtime.h>
#include <stdint.h>

// ---- problem constants (from setup_inputs) ----
static constexpr int NV   = 80000;    // voxels per scale
static constexpr int NPT  = 240000;   // points N
static constexpr int NIMG = 60000;    // B*M image-projected points
static constexpr int Hh   = 64;
static constexpr int Cc   = 20;
static constexpr int NPp  = 120000;   // N per batch
static constexpr int Mm   = 30000;
static constexpr int NB     = 8192;   // error-histogram bins (top-15 float bits)
static constexpr int NCH    = 16;     // chunks per class in hist kernel
static constexpr int NBLK_GA  = (NIMG + 63) / 64;     // 938
static constexpr int NBLK_MLP = NV / 64;              // 1250
static constexpr int NBLK_CNT = (NPT + 255) / 256;    // 938
static constexpr int NBLK_FILL_NV = (NV + 255) / 256;   // 313
static constexpr int NBLK_FILL_NI = (NIMG + 255) / 256; // 235
static constexpr int NBLK_HIST = Cc * NCH;              // 320
static constexpr int NBLK_GATH = 2 * NIMG * 8 / 256;    // 3750 pts-gather rider
static constexpr int NBLK_P3G  = (2 * NIMG + 255) / 256; // 469 pred3d-gather rider
#define BN_EPS 1e-5f

using bf16x8 = __attribute__((ext_vector_type(8))) short;
using f32x4  = __attribute__((ext_vector_type(4))) float;

// ================= small helpers =================
__device__ __forceinline__ float waveReduce(float v) {
  #pragma unroll
  for (int o = 32; o > 0; o >>= 1) v += __shfl_down(v, o);
  return v;
}
__device__ __forceinline__ short f2bf(float f) {   // RNE fp32 -> bf16
  uint32_t u = __float_as_uint(f);
  return (short)((u + 0x7FFFu + ((u >> 16) & 1u)) >> 16);
}
__device__ __forceinline__ float bf2f(uint32_t h) { return __uint_as_float(h << 16); }
__device__ __forceinline__ uint32_t pk2(float a, float b) {
  return ((uint32_t)(uint16_t)f2bf(a)) | ((uint32_t)(uint16_t)f2bf(b) << 16);
}

// ==== D1: pack weights + zero ws + fused idx/pts-gather (high-TLP rider) ===
struct PackDesc { const float* src; short* dst; int K, Nr, nt; };
struct PackArgs { PackDesc d[14]; };

__global__ void __launch_bounds__(256)
k_pack_zero(PackArgs pa,
            const float* __restrict__ fc1w, const float* __restrict__ fc1b,
            const float* __restrict__ fc2w, const float* __restrict__ fc2b,
            const float* __restrict__ fc3w, const float* __restrict__ fc3b,
            float* __restrict__ attEffs,
            uint4* __restrict__ zb, int zq,
            const int* __restrict__ ci0, const int* __restrict__ ci1,
            const int* __restrict__ p2img,
            int* __restrict__ idx0, int* __restrict__ idx1,
            const float* __restrict__ pts, uint16_t* __restrict__ pgath) {
  int bid = blockIdx.x;
  if (bid >= 384) {                              // pts-gather rider: 8 thr/row
    int g = (bid - 384) * 256 + threadIdx.x;     // [0, 2*NIMG*8)
    int row = g >> 3, q = g & 7;                 // row in [0, 2*NIMG)
    int r = (row >= NIMG) ? row - NIMG : row;    // row within scale
    int s1 = (row >= NIMG) ? 1 : 0;
    const int* ci = s1 ? ci1 : ci0;
    int b = (r >= Mm) ? 1 : 0;                   // B=2, contiguous batch blocks
    int id = ci[b * NPp + p2img[r]];
    if (q == 0) { if (s1) idx1[r] = id; else idx0[r] = id; }
    const float* src = pts + (size_t)s1 * NV * 64 + (size_t)id * 64 + q * 8;
    float4 a = *(const float4*)src;
    float4 c = *(const float4*)(src + 4);
    uint4 o;
    o.x = pk2(a.x, a.y); o.y = pk2(a.z, a.w);
    o.z = pk2(c.x, c.y); o.w = pk2(c.z, c.w);
    *(uint4*)(pgath + (size_t)row * 64 + q * 8) = o;
    return;
  }
  if (bid >= 128) {                              // zero rider
    const uint4 z = make_uint4(0u, 0u, 0u, 0u);
    int i = (bid - 128) * 256 + threadIdx.x;
    for (; i < zq; i += 256 * 256) zb[i] = z;
    return;
  }
  const int stride = 128 * 256;
  for (int di = 0; di < 14; di++) {
    const float* src = pa.d[di].src;
    short* dst = pa.d[di].dst;
    int K = pa.d[di].K, Nr = pa.d[di].Nr, ntiles = pa.d[di].nt;
    int total = (K / 32) * ntiles * 512;
    for (int idx = bid * 256 + threadIdx.x; idx < total; idx += stride) {
      int j = idx & 7, lane = (idx >> 3) & 63, tile = idx >> 9;
      int nt = tile % ntiles, kt = tile / ntiles;
      int k = kt * 32 + (lane >> 4) * 8 + j;
      int n = nt * 16 + (lane & 15);
      float v = (n < Nr) ? src[(size_t)k * Nr + n] : 0.f;
      dst[idx] = f2bf(v);
    }
  }
  if (bid < 2 && threadIdx.x < 64) {
    int s = bid, t = threadIdx.x;
    const float* f1w = fc1w + s * 64 * 16; const float* f1b = fc1b + s * 16;
    const float* f2w = fc2w + s * 64 * 16; const float* f2b = fc2b + s * 16;
    const float* f3w = fc3w + s * 64;      const float* f3b = fc3b + s * 2;
    float* aE = attEffs + s * 320;
    float p0 = 0.f, p1 = 0.f, v0 = 0.f, v1 = 0.f;
    #pragma unroll
    for (int j = 0; j < 16; j++) {
      p0 = fmaf(f1w[t * 16 + j], f3w[j * 2], p0);
      p1 = fmaf(f1w[t * 16 + j], f3w[j * 2 + 1], p1);
      v0 = fmaf(f2w[t * 16 + j], f3w[(16 + j) * 2], v0);
      v1 = fmaf(f2w[t * 16 + j], f3w[(16 + j) * 2 + 1], v1);
    }
    aE[t * 2] = p0; aE[t * 2 + 1] = p1;
    aE[128 + t * 2] = v0; aE[128 + t * 2 + 1] = v1;
    if (t == 0) {
      float b0 = f3b[0], b1 = f3b[1];
      for (int j = 0; j < 16; j++) {
        b0 += f1b[j] * f3w[j * 2] + f2b[j] * f3w[(16 + j) * 2];
        b1 += f1b[j] * f3w[j * 2 + 1] + f2b[j] * f3w[(16 + j) * 2 + 1];
      }
      aE[256] = b0; aE[257] = b1;
    }
  }
}

// ====== Lovász scan+bin body — u64 hist layout {lo32=fg, hi32=count} =======
__device__ void scanbin_body(const unsigned long long* __restrict__ H64,
                             int n, int call, float* __restrict__ lossesC5,
                             int* __restrict__ gts5, int cls) {
  __shared__ int sWC[4], sWF[4];
  __shared__ float sRedF[4];
  int t = threadIdx.x;
  int lane = t & 63, w = t >> 6;
  const uint4* Hv = (const uint4*)(H64 + (size_t)cls * NB + (size_t)t * 32);
  int locC = 0, locF = 0;
  #pragma unroll
  for (int i = 0; i < 16; i++) {
    uint4 u = Hv[i];                       // {fg0,cnt0,fg1,cnt1}
    locF += (int)(u.x + u.z);
    locC += (int)(u.y + u.w);
  }
  int sc = locC, sf = locF;
  #pragma unroll
  for (int o = 1; o < 64; o <<= 1) {
    int a = __shfl_up(sc, o);
    int b = __shfl_up(sf, o);
    if (lane >= o) { sc += a; sf += b; }
  }
  if (lane == 63) { sWC[w] = sc; sWF[w] = sf; }
  __syncthreads();
  int offC = 0, offF = 0, Ftot = 0;
  #pragma unroll
  for (int ww = 0; ww < 4; ww++) {
    int fc = sWF[ww];
    Ftot += fc;
    if (ww < w) { offC += sWC[ww]; offF += fc; }
  }
  int runC = offC + sc - locC;    // exclusive prefix (ascending bins)
  int runF = offF + sf - locF;
  float gts = (float)Ftot;
  float contrib = 0.f;
  #pragma unroll
  for (int i = 0; i < 16; i++) {
    uint4 u = Hv[i];
    #pragma unroll
    for (int j = 0; j < 2; j++) {
      int cnt = (int)(j ? u.w : u.y), fgc = (int)(j ? u.z : u.x);
      runC += cnt; runF += fgc;                          // ascending inclusive
      if (cnt > 0 && Ftot > 0) {
        float r0 = (float)(n - runC);
        float F0 = (float)(Ftot - runF);
        float r1 = r0 + (float)cnt;
        float F1 = F0 + (float)fgc;
        float emean = __uint_as_float((uint32_t)(t * 32 + i * 2 + j) << 17);
        contrib += emean * (r1 / (gts + r1 - F1) - r0 / (gts + r0 - F0));
      }
    }
  }
  contrib = waveReduce(contrib);
  if (lane == 0) sRedF[w] = contrib;
  __syncthreads();
  if (t == 0) {
    lossesC5[call * 32 + cls] = (Ftot > 0) ? (sRedF[0] + sRedF[1] + sRedF[2] + sRedF[3]) : 0.f;
    gts5[call * 32 + cls] = Ftot;
  }
}

// ============== per-tile loss epilogue (wave 0, one row/lane) ==============
__device__ void tile_loss(const float* __restrict__ sL, int r0, int rows, int n,
                          const int* __restrict__ lab, uint16_t* __restrict__ E,
                          float ceScale, float* __restrict__ lossAcc) {
  int t = threadIdx.x;
  if (t < 64) {
    float total = 0.f;
    int gr = r0 + t;
    if (gr < rows) {
      const float* l = sL + t * 21;
      float m = l[0];
      #pragma unroll
      for (int c = 1; c < Cc; c++) m = fmaxf(m, l[c]);
      float ex[Cc]; float se = 0.f;
      #pragma unroll
      for (int c = 0; c < Cc; c++) { ex[c] = expf(l[c] - m); se += ex[c]; }
      float inv = 1.f / se;
      float lse = logf(se);
      int lb = lab[gr];
      total = -(l[lb] - m - lse) * ceScale;
      #pragma unroll
      for (int c = 0; c < Cc; c++) {
        float prob = ex[c] * inv;
        int fg = (c == lb) ? 1 : 0;
        float err = fg ? (1.f - prob) : prob;
        err = fmaxf(err, 0.f);
        uint32_t key = __float_as_uint(err) >> 17;     // < 8192
        E[(size_t)c * n + gr] = (uint16_t)((key << 1) | (uint32_t)fg);
      }
    }
    total = waveReduce(total);
    if (t == 0) atomicAdd(lossAcc, total);
  }
}

// ====== MFMA MLP core: relu(X@W1+b1)@W2+b2; out -> global or LDS ==========
template<int D, bool TO_LDS>
__device__ __forceinline__ void mfma_mlp_core(const short* sXb, short* sH, float* sL,
    int r0, int rows,
    const short* __restrict__ pw1, const float* __restrict__ B1,
    const short* __restrict__ pw2, const float* __restrict__ B2,
    float* __restrict__ Out) {
  constexpr int LDB = D + 8;
  constexpr int KT1 = D / 32;
  const int t = threadIdx.x;
  const int lane = t & 63, w = t >> 6;
  const int m = lane & 15, quad = lane >> 4;
  const int rowA = 16 * w + m;
  bf16x8 a1[KT1];
  #pragma unroll
  for (int kt = 0; kt < KT1; kt++)
    a1[kt] = *(const bf16x8*)(sXb + rowA * LDB + kt * 32 + quad * 8);
  __syncthreads();                       // all a1 reads done before sH aliases sXb
  const bf16x8* b1 = (const bf16x8*)pw1;
  #pragma unroll
  for (int nt = 0; nt < 8; nt++) {
    f32x4 c = {0.f, 0.f, 0.f, 0.f};
    #pragma unroll
    for (int kt = 0; kt < KT1; kt++)
      c = __builtin_amdgcn_mfma_f32_16x16x32_bf16(a1[kt], b1[(kt * 8 + nt) * 64 + lane], c, 0, 0, 0);
    int col = nt * 16 + m;
    float bc = B1[col];
    #pragma unroll
    for (int reg = 0; reg < 4; reg++)
      sH[(16 * w + quad * 4 + reg) * 136 + col] = f2bf(fmaxf(c[reg] + bc, 0.f));
  }
  __syncthreads();
  bf16x8 a2[4];
  #pragma unroll
  for (int kt = 0; kt < 4; kt++)
    a2[kt] = *(const bf16x8*)(sH + rowA * 136 + kt * 32 + quad * 8);
  if (TO_LDS) __syncthreads();           // all a2 reads done before sL aliases sH
  const bf16x8* b2 = (const bf16x8*)pw2;
  #pragma unroll
  for (int nt = 0; nt < 2; nt++) {
    f32x4 c = {0.f, 0.f, 0.f, 0.f};
    #pragma unroll
    for (int kt = 0; kt < 4; kt++)
      c = __builtin_amdgcn_mfma_f32_16x16x32_bf16(a2[kt], b2[(kt * 2 + nt) * 64 + lane], c, 0, 0, 0);
    int col = nt * 16 + m;
    if (col < Cc) {
      float bc = B2[col];
      #pragma unroll
      for (int reg = 0; reg < 4; reg++) {
        int rr = 16 * w + quad * 4 + reg;
        if (TO_LDS) {
          sL[rr * 21 + col] = c[reg] + bc;
        } else {
          int gr = r0 + rr;
          if (gr < rows) Out[(size_t)gr * Cc + col] = c[reg] + bc;
        }
      }
    }
  }
}

// ---- MLP D=64, f32 staging, global out (pred3d); buf = 17408 B ----
__device__ void mlp64_body(int bid0, const float* __restrict__ X,
    const short* __restrict__ pw1, const float* __restrict__ B1,
    const short* __restrict__ pw2, const float* __restrict__ B2,
    float* __restrict__ Out, int rows, char* smem) {
  short* buf = (short*)smem;              // sXb (64*72) overlaid by sH (64*136)
  int t = threadIdx.x, r0 = bid0 * 64;
  for (int i = t; i < 1024; i += 256) {
    int r = i >> 4, k4 = (i & 15) * 4;
    int gr = r0 + r;
    float4 v = (gr < rows) ? *(const float4*)(X + (size_t)gr * 64 + k4)
                           : make_float4(0.f, 0.f, 0.f, 0.f);
    uint2 p; p.x = pk2(v.x, v.y); p.y = pk2(v.z, v.w);
    *(uint2*)(buf + r * 72 + k4) = p;
  }
  __syncthreads();
  mfma_mlp_core<64, false>(buf, buf, nullptr, r0, rows, pw1, B1, pw2, B2, Out);
}

// ---- MLP D=128, bf16 staging, fused fill4 loss; buf = 17408 B ----
__device__ void mlp128_loss_body(int bid0, const uint16_t* __restrict__ Xh,
    const short* __restrict__ pw1, const float* __restrict__ B1,
    const short* __restrict__ pw2, const float* __restrict__ B2,
    const int* __restrict__ lab, uint16_t* __restrict__ E, float ce,
    float* __restrict__ lossAcc, char* smem) {
  short* buf = (short*)smem;              // sXb -> sH -> sL overlay
  int t = threadIdx.x, r0 = bid0 * 64;
  for (int i = t; i < 2048; i += 256) {
    int r = i >> 5, k4 = (i & 31) * 4;
    int gr = r0 + r;
    uint2 p = (gr < NIMG) ? *(const uint2*)(Xh + (size_t)gr * 128 + k4) : make_uint2(0u, 0u);
    *(uint2*)(buf + r * 136 + k4) = p;
  }
  __syncthreads();
  mfma_mlp_core<128, true>(buf, buf, (float*)buf, r0, NIMG, pw1, B1, pw2, B2, nullptr);
  __syncthreads();
  tile_loss((float*)buf, r0, NIMG, NIMG, lab, E, ce, lossAcc);
}

// ---- voxel-vote counts ----
__device__ void cnt_body(int bid0, const int* __restrict__ ci, const int* __restrict__ labels,
                         int* __restrict__ counts) {
  int i = bid0 * 256 + threadIdx.x;
  if (i < NPT) atomicAdd(&counts[(size_t)ci[i] * Cc + labels[i]], 1);
}

// ---- pred3d-gather rider: dense p3g[row][20] <- pred3d[idx[row]] ----
__device__ void p3gath_body(int bid0, const float* __restrict__ pred3d0,
                            const float* __restrict__ pred3d1,
                            const int* __restrict__ idx0, const int* __restrict__ idx1,
                            float* __restrict__ p3g0, float* __restrict__ p3g1) {
  int row = bid0 * 256 + threadIdx.x;        // [0, 2*NIMG)
  if (row >= 2 * NIMG) return;
  int s1 = (row >= NIMG) ? 1 : 0;
  int r = s1 ? row - NIMG : row;
  const float* pred = s1 ? pred3d1 : pred3d0;
  float* dst = (s1 ? p3g1 : p3g0) + (size_t)r * Cc;
  const float* src = pred + (size_t)(s1 ? idx1[r] : idx0[r]) * Cc;
  #pragma unroll
  for (int c = 0; c < Cc; c += 2) {
    uint2 v = *(const uint2*)(src + c);      // 8B, rows 8B-aligned (80B stride)
    *(uint2*)(dst + c) = v;
  }
}

// ---- Lovász fill body (CE + optional KL via dense p3g + optional vote) ----
__device__ void fill_body(int bid0, const float* __restrict__ logits,
                          const int* __restrict__ lab, const int* __restrict__ vcnt,
                          int n, uint16_t* __restrict__ E,
                          float ceScale, float* __restrict__ lossAcc,
                          const float* __restrict__ p3g, float klScale) {
  int i = bid0 * 256 + threadIdx.x;
  float total = 0.f;
  if (i < n) {
    int lb;
    if (vcnt) {
      const int* crow = vcnt + (size_t)i * Cc;
      int best = crow[0], arg = 0;
      #pragma unroll
      for (int k = 1; k < Cc; k++) {
        int ck = crow[k];
        if (ck > best) { best = ck; arg = k; }   // first-max
      }
      lb = arg;
    } else {
      lb = lab[i];
    }
    const float* l = logits + (size_t)i * Cc;
    float m = l[0];
    #pragma unroll
    for (int c = 1; c < Cc; c++) m = fmaxf(m, l[c]);
    float ex[Cc]; float se = 0.f;
    #pragma unroll
    for (int c = 0; c < Cc; c++) { ex[c] = expf(l[c] - m); se += ex[c]; }
    float inv = 1.f / se;
    float lse = logf(se);
    total = -(l[lb] - m - lse) * ceScale;
    #pragma unroll
    for (int c = 0; c < Cc; c++) {
      float prob = ex[c] * inv;
      int fg = (c == lb) ? 1 : 0;
      float err = fg ? (1.f - prob) : prob;
      err = fmaxf(err, 0.f);
      uint32_t key = __float_as_uint(err) >> 17;     // < 8192
      E[(size_t)c * n + i] = (uint16_t)((key << 1) | (uint32_t)fg);
    }
    if (p3g) {
      const float* q = p3g + (size_t)i * Cc;         // dense pre-gathered
      float mq = q[0];
      #pragma unroll
      for (int c = 1; c < Cc; c++) mq = fmaxf(mq, q[c]);
      float sq = 0.f;
      #pragma unroll
      for (int c = 0; c < Cc; c++) sq += expf(q[c] - mq);
      float lsq = logf(sq);
      float kl = 0.f;
      #pragma unroll
      for (int c = 0; c < Cc; c++) {
        float lf = l[c] - m - lse;
        float pf = ex[c] * inv;
        float lq = q[c] - mq - lsq;
        kl += pf * (lf - lq);
      }
      total += kl * klScale;
    }
  }
  total = waveReduce(total);
  __shared__ float sh[4];
  int lane = threadIdx.x & 63, w = threadIdx.x >> 6;
  if (lane == 0) sh[w] = total;
  __syncthreads();
  if (threadIdx.x == 0) atomicAdd(lossAcc, sh[0] + sh[1] + sh[2] + sh[3]);
}

// ---- LDS-privatized histogram body (u64 global flush) ----
__device__ void hist_body(int bid0, const uint16_t* __restrict__ E, int n,
                          unsigned long long* __restrict__ H64, char* smem) {
  uint32_t* lcf = (uint32_t*)smem;                 // 8192 u32 = 32 KB
  int t = threadIdx.x;
  int cls = bid0 / NCH, ch = bid0 - cls * NCH;
  int CHsz = (n + NCH - 1) / NCH;
  int i0 = ch * CHsz;
  int i1 = min(n, i0 + CHsz);
  for (int b = t; b < NB; b += 256) lcf[b] = 0u;
  __syncthreads();
  const uint16_t* Ec = E + (size_t)cls * n;
  for (int i = i0 + t; i < i1; i += 256) {
    uint32_t p = Ec[i];
    atomicAdd(&lcf[p >> 1], 0x10000u | (p & 1u));    // count hi16, fg lo16
  }
  __syncthreads();
  unsigned long long* Hc = H64 + (size_t)cls * NB;
  for (int b = t; b < NB; b += 256) {
    uint32_t v = lcf[b];
    if (v)
      atomicAdd(&Hc[b], ((unsigned long long)(v >> 16) << 32) | (v & 0xFFFFu));
  }
}

// ---- dense-staged dual 64x64 GEMM + att + atomic BN accumulation ----
// BN partials accumulated with unsafeAtomicAdd into bnAcc[256] (per scale).
// NO fence/ticket: the next dispatch boundary orders the reads (R1 lesson).
__device__ void gatt_body(int bid0, const uint16_t* __restrict__ pg,
                          const float* __restrict__ img,
                          const short* __restrict__ pc1, const float* __restrict__ c1b,
                          const short* __restrict__ pc2, const float* __restrict__ c2b,
                          const float* __restrict__ attEff,
                          uint16_t* __restrict__ y1, uint16_t* __restrict__ y2,
                          float* __restrict__ attw, float* __restrict__ bnAcc,
                          char* smem) {
  short* sP = (short*)smem;                         // 64*72
  short* sV = (short*)(smem + 9216);                // 64*72
  float* sAtt  = (float*)(smem + 18432);            // 64*8
  float* sStat = (float*)smem;                      // aliases sP (after barrier)
  int t = threadIdx.x;
  int r0 = bid0 * 64;
  for (int i = t; i < 512; i += 256) {
    int r = i >> 3, q = i & 7;
    int gr = r0 + r;
    uint4 pv = make_uint4(0u, 0u, 0u, 0u);
    if (gr < NIMG) pv = *(const uint4*)(pg + (size_t)gr * 64 + q * 8);
    *(uint4*)(sP + r * 72 + q * 8) = pv;
  }
  for (int i = t; i < 1024; i += 256) {
    int r = i >> 4, q = i & 15;
    int gr = r0 + r;
    float4 vv = make_float4(0.f, 0.f, 0.f, 0.f);
    if (gr < NIMG) vv = *(const float4*)(img + (size_t)gr * 64 + q * 4);
    uint2 qv;
    qv.x = pk2(vv.x, vv.y); qv.y = pk2(vv.z, vv.w);
    *(uint2*)(sV + r * 72 + q * 4) = qv;
  }
  __syncthreads();
  {
    int r = t & 63, qq = t >> 6;
    const float* aP = attEff;
    const float* aV = attEff + 128;
    float l0 = 0.f, l1 = 0.f;
    for (int k = qq * 16; k < qq * 16 + 16; k += 4) {
      uint2 up = *(const uint2*)(sP + r * 72 + k);
      uint2 uv = *(const uint2*)(sV + r * 72 + k);
      float p0 = bf2f(up.x & 0xffff), p1 = bf2f(up.x >> 16);
      float p2 = bf2f(up.y & 0xffff), p3 = bf2f(up.y >> 16);
      float v0 = bf2f(uv.x & 0xffff), v1 = bf2f(uv.x >> 16);
      float v2 = bf2f(uv.y & 0xffff), v3 = bf2f(uv.y >> 16);
      float4 wa = *(const float4*)(aP + 2 * k);
      float4 wb = *(const float4*)(aP + 2 * k + 4);
      l0 += p0 * wa.x + p1 * wa.z + p2 * wb.x + p3 * wb.z;
      l1 += p0 * wa.y + p1 * wa.w + p2 * wb.y + p3 * wb.w;
      float4 ua = *(const float4*)(aV + 2 * k);
      float4 ub = *(const float4*)(aV + 2 * k + 4);
      l0 += v0 * ua.x + v1 * ua.z + v2 * ub.x + v3 * ub.z;
      l1 += v0 * ua.y + v1 * ua.w + v2 * ub.y + v3 * ub.w;
    }
    sAtt[r * 8 + qq * 2] = l0;
    sAtt[r * 8 + qq * 2 + 1] = l1;
  }
  const int lane = t & 63, w = t >> 6;
  const int m = lane & 15, quad = lane >> 4;
  const int rowA = 16 * w + m;
  bf16x8 ap[2], av[2];
  #pragma unroll
  for (int kt = 0; kt < 2; kt++) {
    ap[kt] = *(const bf16x8*)(sP + rowA * 72 + kt * 32 + quad * 8);
    av[kt] = *(const bf16x8*)(sV + rowA * 72 + kt * 32 + quad * 8);
  }
  __syncthreads();                 // all sP reads done before sStat aliases it
  const bf16x8* b1 = (const bf16x8*)pc1;
  const bf16x8* b2 = (const bf16x8*)pc2;
  #pragma unroll
  for (int nt = 0; nt < 4; nt++) {
    int col = nt * 16 + m;
    f32x4 c1 = {0.f, 0.f, 0.f, 0.f}, c2 = {0.f, 0.f, 0.f, 0.f};
    #pragma unroll
    for (int kt = 0; kt < 2; kt++) {
      c1 = __builtin_amdgcn_mfma_f32_16x16x32_bf16(ap[kt], b1[(kt * 4 + nt) * 64 + lane], c1, 0, 0, 0);
      c2 = __builtin_amdgcn_mfma_f32_16x16x32_bf16(av[kt], b2[(kt * 4 + nt) * 64 + lane], c2, 0, 0, 0);
    }
    float bb1 = c1b[col], bb2 = c2b[col];
    float s1 = 0.f, q1 = 0.f, s2 = 0.f, q2 = 0.f;
    #pragma unroll
    for (int reg = 0; reg < 4; reg++) {
      int gr = r0 + 16 * w + quad * 4 + reg;
      if (gr < NIMG) {
        float v1 = c1[reg] + bb1, v2 = c2[reg] + bb2;
        y1[(size_t)gr * 64 + col] = (uint16_t)f2bf(v1);
        y2[(size_t)gr * 64 + col] = (uint16_t)f2bf(v2);
        s1 += v1; q1 = fmaf(v1, v1, q1);
        s2 += v2; q2 = fmaf(v2, v2, q2);
      }
    }
    s1 += __shfl_down(s1, 32); s1 += __shfl_down(s1, 16);
    q1 += __shfl_down(q1, 32); q1 += __shfl_down(q1, 16);
    s2 += __shfl_down(s2, 32); s2 += __shfl_down(s2, 16);
    q2 += __shfl_down(q2, 32); q2 += __shfl_down(q2, 16);
    if (lane < 16) {
      float* base = sStat + (w * 4 + nt) * 64 + lane;
      base[0]  = s1;
      base[16] = q1;
      base[32] = s2;
      base[48] = q2;
    }
  }
  __syncthreads();
  {
    int kind = t >> 6, col = t & 63;
    int nt = col >> 4, mm = col & 15;
    float v = 0.f;
    #pragma unroll
    for (int ww = 0; ww < 4; ww++)
      v += sStat[(ww * 4 + nt) * 64 + kind * 16 + mm];
    unsafeAtomicAdd(&bnAcc[t], v);      // bnAcc[kind*64+col] == bnAcc[t]
  }
  if (t < 64) {
    int gr = r0 + t;
    if (gr < NIMG) {
      float l0 = attEff[256] + sAtt[t * 8] + sAtt[t * 8 + 2] + sAtt[t * 8 + 4] + sAtt[t * 8 + 6];
      float l1 = attEff[257] + sAtt[t * 8 + 1] + sAtt[t * 8 + 3] + sAtt[t * 8 + 5] + sAtt[t * 8 + 7];
      attw[gr * 2]     = 1.f / (1.f + expf(-l0));
      attw[gr * 2 + 1] = 1.f / (1.f + expf(-l1));
    }
  }
}

// ---- fuse (BN from bnAcc) -> feats + fuse-MLP (global fusepred) ----
__device__ void fusemlp_body(int bid0,
    const uint16_t* __restrict__ y1, const uint16_t* __restrict__ y2,
    const float* __restrict__ attw, const float* __restrict__ bnAcc,
    const float* __restrict__ g1, const float* __restrict__ be1,
    const float* __restrict__ g2, const float* __restrict__ be2,
    uint16_t* __restrict__ feats, int s64,
    const short* __restrict__ pw1, const float* __restrict__ B1,
    const short* __restrict__ pw2, const float* __restrict__ B2,
    float* __restrict__ Out, char* smem) {
  short* buf = (short*)smem;                    // sSum -> sXb -> sH overlay
  float* sBn = (float*)(smem + 17408);          // 256 floats
  int t = threadIdx.x, r0 = bid0 * 64;
  float* sSum = (float*)buf;                    // scratch
  sSum[t] = bnAcc[t];                           // complete sums from D2 atomics
  __syncthreads();
  if (t < 64) {
    float nn = (float)NIMG;
    float mu1 = sSum[t] / nn;
    float var1 = sSum[64 + t] / nn - mu1 * mu1;
    float a1 = g1[t] / sqrtf(var1 + BN_EPS);
    sBn[t] = a1; sBn[64 + t] = be1[t] - mu1 * a1;
    float mu2 = sSum[128 + t] / nn;
    float var2 = sSum[192 + t] / nn - mu2 * mu2;
    float a2 = g2[t] / sqrtf(var2 + BN_EPS);
    sBn[128 + t] = a2; sBn[192 + t] = be2[t] - mu2 * a2;
  }
  __syncthreads();
  for (int i = t; i < 1024; i += 256) {
    int r = i >> 4, q = i & 15;
    int gr = r0 + r;
    uint2 zp = make_uint2(0u, 0u);
    if (gr < NIMG) {
      float4 a1 = *(const float4*)(sBn + q * 4);
      float4 c1 = *(const float4*)(sBn + 64 + q * 4);
      float4 a2 = *(const float4*)(sBn + 128 + q * 4);
      float4 c2 = *(const float4*)(sBn + 192 + q * 4);
      uint2 u1 = *(const uint2*)(y1 + (size_t)gr * 64 + q * 4);
      uint2 u2 = *(const uint2*)(y2 + (size_t)gr * 64 + q * 4);
      float w0 = attw[gr * 2], w1 = attw[gr * 2 + 1];
      float zx = fmaxf(fmaf(bf2f(u1.x & 0xffff), a1.x, c1.x), 0.f) * w0
               + fmaxf(fmaf(bf2f(u2.x & 0xffff), a2.x, c2.x), 0.f) * w1;
      float zy = fmaxf(fmaf(bf2f(u1.x >> 16),   a1.y, c1.y), 0.f) * w0
               + fmaxf(fmaf(bf2f(u2.x >> 16),   a2.y, c2.y), 0.f) * w1;
      float zz = fmaxf(fmaf(bf2f(u1.y & 0xffff), a1.z, c1.z), 0.f) * w0
               + fmaxf(fmaf(bf2f(u2.y & 0xffff), a2.z, c2.z), 0.f) * w1;
      float zw = fmaxf(fmaf(bf2f(u1.y >> 16),   a1.w, c1.w), 0.f) * w0
               + fmaxf(fmaf(bf2f(u2.y >> 16),   a2.w, c2.w), 0.f) * w1;
      zp.x = pk2(zx, zy); zp.y = pk2(zz, zw);
      *(uint2*)(feats + (size_t)gr * 128 + s64 + q * 4) = zp;
    }
    *(uint2*)(buf + r * 72 + q * 4) = zp;
  }
  __syncthreads();
  mfma_mlp_core<64, false>(buf, buf, nullptr, r0, NIMG, pw1, B1, pw2, B2, Out);
}

// ===================== wrapper kernels (block-range bundles) ===============
// D2: gatt(s0) + gatt(s1) + pred3d MLP x2 + counts x2
__global__ void __launch_bounds__(256)
k_mega2(const float* __restrict__ pf0, const float* __restrict__ pf1,
        const uint16_t* __restrict__ pg0, const uint16_t* __restrict__ pg1,
        const float* __restrict__ if0, const float* __restrict__ if1,
        const short* pc1w0, const short* pc1w1, const short* pc2w0, const short* pc2w1,
        const float* c1b, const float* c2b, const float* attEffs,
        uint16_t* y1a, uint16_t* y2a, uint16_t* y1b, uint16_t* y2b,
        float* attw0, float* attw1, float* bnAcc0, float* bnAcc1,
        const short* pw3a0, const float* b3a, const short* pw3b0, const float* b3b,
        const short* pw3a1, const short* pw3b1,
        float* pred3d0, float* pred3d1,
        const int* __restrict__ ci0, const int* __restrict__ ci1,
        const int* __restrict__ labels,
        int* __restrict__ counts0, int* __restrict__ counts1) {
  __shared__ char smem[20480];
  int bid = blockIdx.x;
  if (bid < NBLK_GA) {
    gatt_body(bid, pg0, if0, pc1w0, c1b, pc2w0, c2b, attEffs,
              y1a, y2a, attw0, bnAcc0, smem);
    return;
  }
  bid -= NBLK_GA;
  if (bid < NBLK_GA) {
    gatt_body(bid, pg1, if1, pc1w1, c1b + 64, pc2w1, c2b + 64, attEffs + 320,
              y1b, y2b, attw1, bnAcc1, smem);
    return;
  }
  bid -= NBLK_GA;
  if (bid < NBLK_MLP) { mlp64_body(bid, pf0, pw3a0, b3a, pw3b0, b3b, pred3d0, NV, smem); return; }
  bid -= NBLK_MLP;
  if (bid < NBLK_MLP) { mlp64_body(bid, pf1, pw3a1, b3a + 128, pw3b1, b3b + Cc, pred3d1, NV, smem); return; }
  bid -= NBLK_MLP;
  if (bid < NBLK_CNT) { cnt_body(bid, ci0, labels, counts0); return; }
  cnt_body(bid - NBLK_CNT, ci1, labels, counts1);
}

// D3: fusemlp x2 (BN from bnAcc) + fill_NV x2 (vote inline) + p3gath rider
__global__ void __launch_bounds__(256)
k_fuse2_fill2(const uint16_t* y1a, const uint16_t* y2a, const float* attw0, const float* bnAcc0,
              const uint16_t* y1b, const uint16_t* y2b, const float* attw1, const float* bnAcc1,
              const float* bn1g, const float* bn1b, const float* bn2g, const float* bn2b,
              uint16_t* feats,
              const short* pwfa0, const float* bfa, const short* pwfb0, const float* bfb,
              const short* pwfa1, const short* pwfb1,
              float* fusepred0, float* fusepred1,
              const float* __restrict__ pred3d0, const int* __restrict__ counts0,
              uint16_t* __restrict__ E0,
              const float* __restrict__ pred3d1, const int* __restrict__ counts1,
              uint16_t* __restrict__ E1,
              float ceNV, float* lossAcc,
              const int* __restrict__ idx0, const int* __restrict__ idx1,
              float* __restrict__ p3g0, float* __restrict__ p3g1) {
  __shared__ char smem[18432];
  int bid = blockIdx.x;
  if (bid < NBLK_GA) {
    fusemlp_body(bid, y1a, y2a, attw0, bnAcc0, bn1g, bn1b, bn2g, bn2b, feats, 0,
                 pwfa0, bfa, pwfb0, bfb, fusepred0, smem);
    return;
  }
  bid -= NBLK_GA;
  if (bid < NBLK_GA) {
    fusemlp_body(bid, y1b, y2b, attw1, bnAcc1, bn1g + 64, bn1b + 64, bn2g + 64, bn2b + 64,
                 feats, 64, pwfa1, bfa + 128, pwfb1, bfb + Cc, fusepred1, smem);
    return;
  }
  bid -= NBLK_GA;
  if (bid < NBLK_FILL_NV) {
    fill_body(bid, pred3d0, nullptr, counts0, NV, E0, ceNV, lossAcc, nullptr, 0.f);
    return;
  }
  bid -= NBLK_FILL_NV;
  if (bid < NBLK_FILL_NV) {
    fill_body(bid, pred3d1, nullptr, counts1, NV, E1, ceNV, lossAcc, nullptr, 0.f);
    return;
  }
  p3gath_body(bid - NBLK_FILL_NV, pred3d0, pred3d1, idx0, idx1, p3g0, p3g1);
}

// D4: final MLP (fused fill4 -> E2) + fill1 + fill3 + hist0 + hist2
__global__ void __launch_bounds__(256)
k_finx2(const uint16_t* __restrict__ feats,
        const short* pcl1, const float* clb1, const short* pcl2, const float* clb2,
        const int* __restrict__ img_label, uint16_t* E2, float ce4, float* lossAcc,
        const float* fusepred0, const float* p3g0, uint16_t* E3,
        const float* fusepred1, const float* p3g1, uint16_t* E4,
        float ce, float kl,
        const uint16_t* __restrict__ E0, unsigned long long* H0,
        const uint16_t* __restrict__ E1, unsigned long long* H2) {
  __shared__ char smem[32768];
  int bid = blockIdx.x;
  if (bid < NBLK_GA) {
    mlp128_loss_body(bid, feats, pcl1, clb1, pcl2, clb2, img_label, E2, ce4, lossAcc, smem);
    return;
  }
  bid -= NBLK_GA;
  if (bid < NBLK_FILL_NI) {
    fill_body(bid, fusepred0, img_label, nullptr, NIMG, E3, ce, lossAcc, p3g0, kl);
    return;
  }
  bid -= NBLK_FILL_NI;
  if (bid < NBLK_FILL_NI) {
    fill_body(bid, fusepred1, img_label, nullptr, NIMG, E4, ce, lossAcc, p3g1, kl);
    return;
  }
  bid -= NBLK_FILL_NI;
  if (bid < NBLK_HIST) { hist_body(bid, E0, NV, H0, smem); return; }
  hist_body(bid - NBLK_HIST, E1, NV, H2, smem);
}

// D5: hist1(E3) + hist3(E4) + hist4(E2) + scan0 + scan2
__global__ void __launch_bounds__(256)
k_hist3_scan2(const uint16_t* __restrict__ E3, unsigned long long* H1,
              const uint16_t* __restrict__ E4, unsigned long long* H3,
              const uint16_t* __restrict__ E2, unsigned long long* H4,
              const unsigned long long* H0, const unsigned long long* H2s,
              float* lossesC5, int* gts5) {
  __shared__ char smem[32768];
  int bid = blockIdx.x;
  if (bid < NBLK_HIST) { hist_body(bid, E3, NIMG, H1, smem); return; }
  bid -= NBLK_HIST;
  if (bid < NBLK_HIST) { hist_body(bid, E4, NIMG, H3, smem); return; }
  bid -= NBLK_HIST;
  if (bid < NBLK_HIST) { hist_body(bid, E2, NIMG, H4, smem); return; }
  bid -= NBLK_HIST;
  if (bid < Cc) { scanbin_body(H0, NV, 0, lossesC5, gts5, bid); return; }
  scanbin_body(H2s, NV, 2, lossesC5, gts5, bid - Cc);
}

// D6: scan1 + scan3 + scan4
__global__ void __launch_bounds__(256)
k_scan3(const unsigned long long* H1, const unsigned long long* H3,
        const unsigned long long* H4,
        float* lossesC5, int* gts5) {
  int bid = blockIdx.x;
  if (bid < Cc) { scanbin_body(H1, NIMG, 1, lossesC5, gts5, bid); return; }
  bid -= Cc;
  if (bid < Cc) { scanbin_body(H3, NIMG, 3, lossesC5, gts5, bid); return; }
  scanbin_body(H4, NIMG, 4, lossesC5, gts5, bid - Cc);
}

// D7: fold 5 lovász combines + output
__global__ void k_final(const float* __restrict__ lossAcc,
                        const float* __restrict__ lossesC5, const int* __restrict__ gts5,
                        float* __restrict__ out) {
  const float coefs[5] = {1.0f, 0.5f, 1.0f, 0.5f, 1.0f};
  float loss = lossAcc[0];
  for (int call = 0; call < 5; call++) {
    float s = 0.f; int np = 0;
    for (int c = 0; c < Cc; c++)
      if (gts5[call * 32 + c] > 0) { s += lossesC5[call * 32 + c]; np++; }
    loss += coefs[call] * s / (float)(np > 0 ? np : 1);
  }
  out[0] = loss;
}

// ================= host-side driver =================
extern "C" void kernel_launch(void* const* d_in, const int* in_sizes, int n_in,
                              void* d_out, int out_size, void* d_ws, size_t ws_size,
                              hipStream_t stream) {
  const float* img_feat = (const float*)d_in[0];
  const float* pts_feat = (const float*)d_in[1];
  const int* coors_inv  = (const int*)d_in[2];
  const int* labels     = (const int*)d_in[3];
  const int* img_label  = (const int*)d_in[4];
  const int* p2img      = (const int*)d_in[5];
  const float* w3a = (const float*)d_in[6];
  const float* b3a = (const float*)d_in[7];
  const float* w3b = (const float*)d_in[8];
  const float* b3b = (const float*)d_in[9];
  const float* wfa = (const float*)d_in[10];
  const float* bfa = (const float*)d_in[11];
  const float* wfb = (const float*)d_in[12];
  const float* bfb = (const float*)d_in[13];
  const float* fc1w = (const float*)d_in[14];
  const float* fc1b = (const float*)d_in[15];
  const float* fc2w = (const float*)d_in[16];
  const float* fc2b = (const float*)d_in[17];
  const float* fc3w = (const float*)d_in[18];
  const float* fc3b = (const float*)d_in[19];
  const float* c1w  = (const float*)d_in[20];
  const float* c1b  = (const float*)d_in[21];
  const float* bn1g = (const float*)d_in[22];
  const float* bn1b = (const float*)d_in[23];
  const float* c2w  = (const float*)d_in[24];
  const float* c2b  = (const float*)d_in[25];
  const float* bn2g = (const float*)d_in[26];
  const float* bn2b = (const float*)d_in[27];
  const float* clw1 = (const float*)d_in[28];
  const float* clb1 = (const float*)d_in[29];
  const float* clw2 = (const float*)d_in[30];
  const float* clb2 = (const float*)d_in[31];
  (void)in_sizes; (void)n_in; (void)out_size; (void)ws_size;

  // ---- workspace layout ----
  char* ws = (char*)d_ws;
  size_t off = 0;
  auto alloc = [&](size_t bytes) { void* p = ws + off; off += (bytes + 255) & ~(size_t)255; return p; };
  uint16_t* feats = (uint16_t*)alloc((size_t)NIMG * 128 * 2);
  uint16_t* pgath = (uint16_t*)alloc((size_t)2 * NIMG * 64 * 2);  // dense gathered pts (bf16)
  float* pred3d0 = (float*)alloc((size_t)NV * Cc * 4);
  float* pred3d1 = (float*)alloc((size_t)NV * Cc * 4);
  float* p3g0 = (float*)alloc((size_t)NIMG * Cc * 4);             // dense gathered pred3d
  float* p3g1 = (float*)alloc((size_t)NIMG * Cc * 4);
  int* idx0 = (int*)alloc((size_t)NIMG * 4);
  int* idx1 = (int*)alloc((size_t)NIMG * 4);
  uint16_t* y1a = (uint16_t*)alloc((size_t)NIMG * Hh * 2);
  uint16_t* y2a = (uint16_t*)alloc((size_t)NIMG * Hh * 2);
  uint16_t* y1b = (uint16_t*)alloc((size_t)NIMG * Hh * 2);
  uint16_t* y2b = (uint16_t*)alloc((size_t)NIMG * Hh * 2);
  uint16_t* E0 = (uint16_t*)alloc((size_t)Cc * NV * 2);
  uint16_t* E1 = (uint16_t*)alloc((size_t)Cc * NV * 2);
  uint16_t* E2 = (uint16_t*)alloc((size_t)Cc * NIMG * 2);
  uint16_t* E3 = (uint16_t*)alloc((size_t)Cc * NIMG * 2);
  uint16_t* E4 = (uint16_t*)alloc((size_t)Cc * NIMG * 2);
  float* attw0 = (float*)alloc((size_t)NIMG * 2 * 4);
  float* attw1 = (float*)alloc((size_t)NIMG * 2 * 4);
  float* fusepred0 = (float*)alloc((size_t)NIMG * Cc * 4);
  float* fusepred1 = (float*)alloc((size_t)NIMG * Cc * 4);
  short* pwAll = (short*)alloc(86016 * 2);
  short* pw3a0 = pwAll,          * pw3a1 = pwAll + 8192;
  short* pwfa0 = pwAll + 16384,  * pwfa1 = pwAll + 24576;
  short* pw3b0 = pwAll + 32768,  * pw3b1 = pwAll + 36864;
  short* pwfb0 = pwAll + 40960,  * pwfb1 = pwAll + 45056;
  short* pcl1  = pwAll + 49152;
  short* pcl2  = pwAll + 65536;
  short* pc1w0 = pwAll + 69632,  * pc1w1 = pwAll + 73728;
  short* pc2w0 = pwAll + 77824,  * pc2w1 = pwAll + 81920;
  float* attEffs = (float*)alloc(2 * 320 * 4);
  // ---- contiguous zero region: stats(4096B, incl bnAcc) + 5x u64 hist + counts ----
  size_t zsize = 4096 + (size_t)5 * Cc * NB * 8 + (size_t)2 * NV * Cc * 4;
  char* zbase = (char*)alloc(zsize);
  float* lossAcc  = (float*)zbase;                 // [0]
  float* lossesC5 = (float*)zbase + 32;            // 5*32 floats (bytes 128..768)
  int*   gts5     = (int*)((float*)zbase + 192);   // 5*32 ints (bytes 768..1408)
  float* bnAcc0   = (float*)(zbase + 1536);        // 256 floats
  float* bnAcc1   = (float*)(zbase + 2560);        // 256 floats (ends 3584 < 4096)
  unsigned long long* Hbase = (unsigned long long*)(zbase + 4096);
  auto Hc = [&](int call) { return Hbase + (size_t)call * Cc * NB; };
  int* counts0 = (int*)(zbase + 4096 + (size_t)5 * Cc * NB * 8);
  int* counts1 = counts0 + (size_t)NV * Cc;
  int zq = (int)(zsize / 16);

  const float kl = 0.025f / ((float)NIMG * Cc);
  const float* pf0 = pts_feat;
  const float* pf1 = pts_feat + (size_t)NV * Hh;
  const float* if0 = img_feat;
  const float* if1 = img_feat + (size_t)NIMG * Hh;
  const int* ci0 = coors_inv;
  const int* ci1 = coors_inv + NPT;
  uint16_t* pg0 = pgath;
  uint16_t* pg1 = pgath + (size_t)NIMG * 64;

  // D1: pack weights + zero ws region + fused idx/pts-gather
  PackArgs pa;
  pa.d[0]  = {w3a,        pw3a0, 64, 128, 8};
  pa.d[1]  = {w3a + 8192, pw3a1, 64, 128, 8};
  pa.d[2]  = {wfa,        pwfa0, 64, 128, 8};
  pa.d[3]  = {wfa + 8192, pwfa1, 64, 128, 8};
  pa.d[4]  = {w3b,        pw3b0, 128, 20, 2};
  pa.d[5]  = {w3b + 2560, pw3b1, 128, 20, 2};
  pa.d[6]  = {wfb,        pwfb0, 128, 20, 2};
  pa.d[7]  = {wfb + 2560, pwfb1, 128, 20, 2};
  pa.d[8]  = {clw1,       pcl1, 128, 128, 8};
  pa.d[9]  = {clw2,       pcl2, 128, 20, 2};
  pa.d[10] = {c1w,        pc1w0, 64, 64, 4};
  pa.d[11] = {c1w + 4096, pc1w1, 64, 64, 4};
  pa.d[12] = {c2w,        pc2w0, 64, 64, 4};
  pa.d[13] = {c2w + 4096, pc2w1, 64, 64, 4};
  k_pack_zero<<<384 + NBLK_GATH, 256, 0, stream>>>(
      pa, fc1w, fc1b, fc2w, fc2b, fc3w, fc3b, attEffs,
      (uint4*)zbase, zq, ci0, ci1, p2img, idx0, idx1, pts_feat, pgath);

  // D2: gatt x2 (atomic BN) + pred3d MLP x2 + counts x2
  k_mega2<<<2 * NBLK_GA + 2 * NBLK_MLP + 2 * NBLK_CNT, 256, 0, stream>>>(
      pf0, pf1, pg0, pg1, if0, if1,
      pc1w0, pc1w1, pc2w0, pc2w1, c1b, c2b, attEffs,
      y1a, y2a, y1b, y2b, attw0, attw1, bnAcc0, bnAcc1,
      pw3a0, b3a, pw3b0, b3b, pw3a1, pw3b1, pred3d0, pred3d1,
      ci0, ci1, labels, counts0, counts1);

  // D3: fusemlp x2 (BN from bnAcc) + fill_NV x2 (vote inline) + p3gath
  k_fuse2_fill2<<<2 * NBLK_GA + 2 * NBLK_FILL_NV + NBLK_P3G, 256, 0, stream>>>(
      y1a, y2a, attw0, bnAcc0, y1b, y2b, attw1, bnAcc1,
      bn1g, bn1b, bn2g, bn2b, feats,
      pwfa0, bfa, pwfb0, bfb, pwfa1, pwfb1, fusepred0, fusepred1,
      pred3d0, counts0, E0, pred3d1, counts1, E1,
      1.0f / NV, lossAcc,
      idx0, idx1, p3g0, p3g1);

  // D4: final MLP (+fused fill4 -> E2) + fill1 + fill3 + hist0 + hist2
  k_finx2<<<NBLK_GA + 2 * NBLK_FILL_NI + 2 * NBLK_HIST, 256, 0, stream>>>(
      feats, pcl1, clb1, pcl2, clb2,
      img_label, E2, 1.0f / NIMG, lossAcc,
      fusepred0, p3g0, E3,
      fusepred1, p3g1, E4,
      0.5f / NIMG, kl,
      E0, Hc(0), E1, Hc(2));

  // D5: hist1 + hist3 + hist4 + scan0 + scan2
  k_hist3_scan2<<<3 * NBLK_HIST + 2 * Cc, 256, 0, stream>>>(
      E3, Hc(1), E4, Hc(3), E2, Hc(4),
      Hc(0), Hc(2), lossesC5, gts5);

  // D6: scan1 + scan3 + scan4
  k_scan3<<<3 * Cc, 256, 0, stream>>>(Hc(1), Hc(3), Hc(4), lossesC5, gts5);

  // D7: fold + output
  k_final<<<1, 1, 0, stream>>>(lossAcc, lossesC5, gts5, (float*)d_out);
}

// Round 13
// 333.396 us; speedup vs baseline: 1.0419x; 1.0419x over previous
//
#include <hip/hip_runtime.h>
#include <stdint.h>

// ---- problem constants (from setup_inputs) ----
static constexpr int NV   = 80000;    // voxels per scale
static constexpr int NPT  = 240000;   // points N
static constexpr int NIMG = 60000;    // B*M image-projected points
static constexpr int Hh   = 64;
static constexpr int Cc   = 20;
static constexpr int NPp  = 120000;   // N per batch
static constexpr int Mm   = 30000;
static constexpr int NB     = 8192;   // error-histogram bins (top-15 float bits)
static constexpr int NCH    = 16;     // chunks per class in hist kernel
static constexpr int NBLK_GA  = (NIMG + 63) / 64;     // 938
static constexpr int NBLK_MLP = NV / 64;              // 1250
static constexpr int NBLK_CNT = (NPT + 255) / 256;    // 938
static constexpr int NBLK_FILL_NV = (NV + 255) / 256;   // 313
static constexpr int NBLK_FILL_NI = (NIMG + 255) / 256; // 235
static constexpr int NBLK_HIST = Cc * NCH;              // 320
static constexpr int NBLK_GATH = 2 * NIMG * 8 / 256;    // 3750 pts-gather rider
static constexpr int NBLK_P3G  = (2 * NIMG + 255) / 256; // 469 pred3d-gather rider
#define BN_EPS 1e-5f

using bf16x8 = __attribute__((ext_vector_type(8))) short;
using f32x4  = __attribute__((ext_vector_type(4))) float;

// ================= small helpers =================
__device__ __forceinline__ float waveReduce(float v) {
  #pragma unroll
  for (int o = 32; o > 0; o >>= 1) v += __shfl_down(v, o);
  return v;
}
__device__ __forceinline__ short f2bf(float f) {   // RNE fp32 -> bf16
  uint32_t u = __float_as_uint(f);
  return (short)((u + 0x7FFFu + ((u >> 16) & 1u)) >> 16);
}
__device__ __forceinline__ float bf2f(uint32_t h) { return __uint_as_float(h << 16); }
__device__ __forceinline__ uint32_t pk2(float a, float b) {
  return ((uint32_t)(uint16_t)f2bf(a)) | ((uint32_t)(uint16_t)f2bf(b) << 16);
}

// ==== D1: pack weights + zero ws + fused idx/pts-gather (high-TLP rider) ===
struct PackDesc { const float* src; short* dst; int K, Nr, nt; };
struct PackArgs { PackDesc d[14]; };

__global__ void __launch_bounds__(256)
k_pack_zero(PackArgs pa,
            const float* __restrict__ fc1w, const float* __restrict__ fc1b,
            const float* __restrict__ fc2w, const float* __restrict__ fc2b,
            const float* __restrict__ fc3w, const float* __restrict__ fc3b,
            float* __restrict__ attEffs,
            uint4* __restrict__ zb, int zq,
            const int* __restrict__ ci0, const int* __restrict__ ci1,
            const int* __restrict__ p2img,
            int* __restrict__ idx0, int* __restrict__ idx1,
            const float* __restrict__ pts, uint16_t* __restrict__ pgath) {
  int bid = blockIdx.x;
  if (bid >= 384) {                              // pts-gather rider: 8 thr/row
    int g = (bid - 384) * 256 + threadIdx.x;     // [0, 2*NIMG*8)
    int row = g >> 3, q = g & 7;                 // row in [0, 2*NIMG)
    int r = (row >= NIMG) ? row - NIMG : row;    // row within scale
    int s1 = (row >= NIMG) ? 1 : 0;
    const int* ci = s1 ? ci1 : ci0;
    int b = (r >= Mm) ? 1 : 0;                   // B=2, contiguous batch blocks
    int id = ci[b * NPp + p2img[r]];
    if (q == 0) { if (s1) idx1[r] = id; else idx0[r] = id; }
    const float* src = pts + (size_t)s1 * NV * 64 + (size_t)id * 64 + q * 8;
    float4 a = *(const float4*)src;
    float4 c = *(const float4*)(src + 4);
    uint4 o;
    o.x = pk2(a.x, a.y); o.y = pk2(a.z, a.w);
    o.z = pk2(c.x, c.y); o.w = pk2(c.z, c.w);
    *(uint4*)(pgath + (size_t)row * 64 + q * 8) = o;
    return;
  }
  if (bid >= 128) {                              // zero rider
    const uint4 z = make_uint4(0u, 0u, 0u, 0u);
    int i = (bid - 128) * 256 + threadIdx.x;
    for (; i < zq; i += 256 * 256) zb[i] = z;
    return;
  }
  const int stride = 128 * 256;
  for (int di = 0; di < 14; di++) {
    const float* src = pa.d[di].src;
    short* dst = pa.d[di].dst;
    int K = pa.d[di].K, Nr = pa.d[di].Nr, ntiles = pa.d[di].nt;
    int total = (K / 32) * ntiles * 512;
    for (int idx = bid * 256 + threadIdx.x; idx < total; idx += stride) {
      int j = idx & 7, lane = (idx >> 3) & 63, tile = idx >> 9;
      int nt = tile % ntiles, kt = tile / ntiles;
      int k = kt * 32 + (lane >> 4) * 8 + j;
      int n = nt * 16 + (lane & 15);
      float v = (n < Nr) ? src[(size_t)k * Nr + n] : 0.f;
      dst[idx] = f2bf(v);
    }
  }
  if (bid < 2 && threadIdx.x < 64) {
    int s = bid, t = threadIdx.x;
    const float* f1w = fc1w + s * 64 * 16; const float* f1b = fc1b + s * 16;
    const float* f2w = fc2w + s * 64 * 16; const float* f2b = fc2b + s * 16;
    const float* f3w = fc3w + s * 64;      const float* f3b = fc3b + s * 2;
    float* aE = attEffs + s * 320;
    float p0 = 0.f, p1 = 0.f, v0 = 0.f, v1 = 0.f;
    #pragma unroll
    for (int j = 0; j < 16; j++) {
      p0 = fmaf(f1w[t * 16 + j], f3w[j * 2], p0);
      p1 = fmaf(f1w[t * 16 + j], f3w[j * 2 + 1], p1);
      v0 = fmaf(f2w[t * 16 + j], f3w[(16 + j) * 2], v0);
      v1 = fmaf(f2w[t * 16 + j], f3w[(16 + j) * 2 + 1], v1);
    }
    aE[t * 2] = p0; aE[t * 2 + 1] = p1;
    aE[128 + t * 2] = v0; aE[128 + t * 2 + 1] = v1;
    if (t == 0) {
      float b0 = f3b[0], b1 = f3b[1];
      for (int j = 0; j < 16; j++) {
        b0 += f1b[j] * f3w[j * 2] + f2b[j] * f3w[(16 + j) * 2];
        b1 += f1b[j] * f3w[j * 2 + 1] + f2b[j] * f3w[(16 + j) * 2 + 1];
      }
      aE[256] = b0; aE[257] = b1;
    }
  }
}

// ====== Lovász scan+bin body — u64 hist layout {lo32=fg, hi32=count} =======
__device__ void scanbin_body(const unsigned long long* __restrict__ H64,
                             int n, int call, float* __restrict__ lossesC5,
                             int* __restrict__ gts5, int cls) {
  __shared__ int sWC[4], sWF[4];
  __shared__ float sRedF[4];
  int t = threadIdx.x;
  int lane = t & 63, w = t >> 6;
  const uint4* Hv = (const uint4*)(H64 + (size_t)cls * NB + (size_t)t * 32);
  int locC = 0, locF = 0;
  #pragma unroll
  for (int i = 0; i < 16; i++) {
    uint4 u = Hv[i];                       // {fg0,cnt0,fg1,cnt1}
    locF += (int)(u.x + u.z);
    locC += (int)(u.y + u.w);
  }
  int sc = locC, sf = locF;
  #pragma unroll
  for (int o = 1; o < 64; o <<= 1) {
    int a = __shfl_up(sc, o);
    int b = __shfl_up(sf, o);
    if (lane >= o) { sc += a; sf += b; }
  }
  if (lane == 63) { sWC[w] = sc; sWF[w] = sf; }
  __syncthreads();
  int offC = 0, offF = 0, Ftot = 0;
  #pragma unroll
  for (int ww = 0; ww < 4; ww++) {
    int fc = sWF[ww];
    Ftot += fc;
    if (ww < w) { offC += sWC[ww]; offF += fc; }
  }
  int runC = offC + sc - locC;    // exclusive prefix (ascending bins)
  int runF = offF + sf - locF;
  float gts = (float)Ftot;
  float contrib = 0.f;
  #pragma unroll
  for (int i = 0; i < 16; i++) {
    uint4 u = Hv[i];
    #pragma unroll
    for (int j = 0; j < 2; j++) {
      int cnt = (int)(j ? u.w : u.y), fgc = (int)(j ? u.z : u.x);
      runC += cnt; runF += fgc;                          // ascending inclusive
      if (cnt > 0 && Ftot > 0) {
        float r0 = (float)(n - runC);
        float F0 = (float)(Ftot - runF);
        float r1 = r0 + (float)cnt;
        float F1 = F0 + (float)fgc;
        float emean = __uint_as_float((uint32_t)(t * 32 + i * 2 + j) << 17);
        contrib += emean * (r1 / (gts + r1 - F1) - r0 / (gts + r0 - F0));
      }
    }
  }
  contrib = waveReduce(contrib);
  if (lane == 0) sRedF[w] = contrib;
  __syncthreads();
  if (t == 0) {
    lossesC5[call * 32 + cls] = (Ftot > 0) ? (sRedF[0] + sRedF[1] + sRedF[2] + sRedF[3]) : 0.f;
    gts5[call * 32 + cls] = Ftot;
  }
}

// ============== per-tile loss epilogue (wave 0, one row/lane) ==============
__device__ void tile_loss(const float* __restrict__ sL, int r0, int rows, int n,
                          const int* __restrict__ lab, uint16_t* __restrict__ E,
                          float ceScale, float* __restrict__ lossAcc) {
  int t = threadIdx.x;
  if (t < 64) {
    float total = 0.f;
    int gr = r0 + t;
    if (gr < rows) {
      const float* l = sL + t * 21;
      float m = l[0];
      #pragma unroll
      for (int c = 1; c < Cc; c++) m = fmaxf(m, l[c]);
      float ex[Cc]; float se = 0.f;
      #pragma unroll
      for (int c = 0; c < Cc; c++) { ex[c] = expf(l[c] - m); se += ex[c]; }
      float inv = 1.f / se;
      float lse = logf(se);
      int lb = lab[gr];
      total = -(l[lb] - m - lse) * ceScale;
      #pragma unroll
      for (int c = 0; c < Cc; c++) {
        float prob = ex[c] * inv;
        int fg = (c == lb) ? 1 : 0;
        float err = fg ? (1.f - prob) : prob;
        err = fmaxf(err, 0.f);
        uint32_t key = __float_as_uint(err) >> 17;     // < 8192
        E[(size_t)c * n + gr] = (uint16_t)((key << 1) | (uint32_t)fg);
      }
    }
    total = waveReduce(total);
    if (t == 0) atomicAdd(lossAcc, total);
  }
}

// ====== MFMA MLP core: relu(X@W1+b1)@W2+b2; out -> global or LDS ==========
// OVERLAY: sXb/sH/sL all share one buffer; barriers fence each alias switch.
template<int D, bool TO_LDS>
__device__ __forceinline__ void mfma_mlp_core(const short* sXb, short* sH, float* sL,
    int r0, int rows,
    const short* __restrict__ pw1, const float* __restrict__ B1,
    const short* __restrict__ pw2, const float* __restrict__ B2,
    float* __restrict__ Out) {
  constexpr int LDB = D + 8;
  constexpr int KT1 = D / 32;
  const int t = threadIdx.x;
  const int lane = t & 63, w = t >> 6;
  const int m = lane & 15, quad = lane >> 4;
  const int rowA = 16 * w + m;
  bf16x8 a1[KT1];
  #pragma unroll
  for (int kt = 0; kt < KT1; kt++)
    a1[kt] = *(const bf16x8*)(sXb + rowA * LDB + kt * 32 + quad * 8);
  __syncthreads();                       // all a1 reads done before sH aliases sXb
  const bf16x8* b1 = (const bf16x8*)pw1;
  #pragma unroll
  for (int nt = 0; nt < 8; nt++) {
    f32x4 c = {0.f, 0.f, 0.f, 0.f};
    #pragma unroll
    for (int kt = 0; kt < KT1; kt++)
      c = __builtin_amdgcn_mfma_f32_16x16x32_bf16(a1[kt], b1[(kt * 8 + nt) * 64 + lane], c, 0, 0, 0);
    int col = nt * 16 + m;
    float bc = B1[col];
    #pragma unroll
    for (int reg = 0; reg < 4; reg++)
      sH[(16 * w + quad * 4 + reg) * 136 + col] = f2bf(fmaxf(c[reg] + bc, 0.f));
  }
  __syncthreads();
  bf16x8 a2[4];
  #pragma unroll
  for (int kt = 0; kt < 4; kt++)
    a2[kt] = *(const bf16x8*)(sH + rowA * 136 + kt * 32 + quad * 8);
  if (TO_LDS) __syncthreads();           // all a2 reads done before sL aliases sH
  const bf16x8* b2 = (const bf16x8*)pw2;
  #pragma unroll
  for (int nt = 0; nt < 2; nt++) {
    f32x4 c = {0.f, 0.f, 0.f, 0.f};
    #pragma unroll
    for (int kt = 0; kt < 4; kt++)
      c = __builtin_amdgcn_mfma_f32_16x16x32_bf16(a2[kt], b2[(kt * 2 + nt) * 64 + lane], c, 0, 0, 0);
    int col = nt * 16 + m;
    if (col < Cc) {
      float bc = B2[col];
      #pragma unroll
      for (int reg = 0; reg < 4; reg++) {
        int rr = 16 * w + quad * 4 + reg;
        if (TO_LDS) {
          sL[rr * 21 + col] = c[reg] + bc;
        } else {
          int gr = r0 + rr;
          if (gr < rows) Out[(size_t)gr * Cc + col] = c[reg] + bc;
        }
      }
    }
  }
}

// ---- MLP D=64, f32 staging, global out (pred3d); buf = 17408 B ----
__device__ void mlp64_body(int bid0, const float* __restrict__ X,
    const short* __restrict__ pw1, const float* __restrict__ B1,
    const short* __restrict__ pw2, const float* __restrict__ B2,
    float* __restrict__ Out, int rows, char* smem) {
  short* buf = (short*)smem;              // sXb (64*72) overlaid by sH (64*136)
  int t = threadIdx.x, r0 = bid0 * 64;
  for (int i = t; i < 1024; i += 256) {
    int r = i >> 4, k4 = (i & 15) * 4;
    int gr = r0 + r;
    float4 v = (gr < rows) ? *(const float4*)(X + (size_t)gr * 64 + k4)
                           : make_float4(0.f, 0.f, 0.f, 0.f);
    uint2 p; p.x = pk2(v.x, v.y); p.y = pk2(v.z, v.w);
    *(uint2*)(buf + r * 72 + k4) = p;
  }
  __syncthreads();
  mfma_mlp_core<64, false>(buf, buf, nullptr, r0, rows, pw1, B1, pw2, B2, Out);
}

// ---- MLP D=128, bf16 staging, fused fill4 loss; buf = 17408 B ----
__device__ void mlp128_loss_body(int bid0, const uint16_t* __restrict__ Xh,
    const short* __restrict__ pw1, const float* __restrict__ B1,
    const short* __restrict__ pw2, const float* __restrict__ B2,
    const int* __restrict__ lab, uint16_t* __restrict__ E, float ce,
    float* __restrict__ lossAcc, char* smem) {
  short* buf = (short*)smem;              // sXb -> sH -> sL overlay
  int t = threadIdx.x, r0 = bid0 * 64;
  for (int i = t; i < 2048; i += 256) {
    int r = i >> 5, k4 = (i & 31) * 4;
    int gr = r0 + r;
    uint2 p = (gr < NIMG) ? *(const uint2*)(Xh + (size_t)gr * 128 + k4) : make_uint2(0u, 0u);
    *(uint2*)(buf + r * 136 + k4) = p;
  }
  __syncthreads();
  mfma_mlp_core<128, true>(buf, buf, (float*)buf, r0, NIMG, pw1, B1, pw2, B2, nullptr);
  __syncthreads();
  tile_loss((float*)buf, r0, NIMG, NIMG, lab, E, ce, lossAcc);
}

// ---- voxel-vote counts ----
__device__ void cnt_body(int bid0, const int* __restrict__ ci, const int* __restrict__ labels,
                         int* __restrict__ counts) {
  int i = bid0 * 256 + threadIdx.x;
  if (i < NPT) atomicAdd(&counts[(size_t)ci[i] * Cc + labels[i]], 1);
}

// ---- BN partials column-reduce ----
__device__ void colred_body(int bid0, const float* __restrict__ partials,
                            float* __restrict__ red64) {
  int t = threadIdx.x, j = bid0;
  float v = 0.f;
  for (int b = j; b < NBLK_GA; b += 64) v += partials[(size_t)b * 256 + t];
  red64[j * 256 + t] = v;
}

// ---- pred3d-gather rider: dense p3g[row][20] <- pred3d[idx[row]] ----
__device__ void p3gath_body(int bid0, const float* __restrict__ pred3d0,
                            const float* __restrict__ pred3d1,
                            const int* __restrict__ idx0, const int* __restrict__ idx1,
                            float* __restrict__ p3g0, float* __restrict__ p3g1) {
  int row = bid0 * 256 + threadIdx.x;        // [0, 2*NIMG)
  if (row >= 2 * NIMG) return;
  int s1 = (row >= NIMG) ? 1 : 0;
  int r = s1 ? row - NIMG : row;
  const float* pred = s1 ? pred3d1 : pred3d0;
  float* dst = (s1 ? p3g1 : p3g0) + (size_t)r * Cc;
  const float* src = pred + (size_t)(s1 ? idx1[r] : idx0[r]) * Cc;
  #pragma unroll
  for (int c = 0; c < Cc; c += 2) {
    uint2 v = *(const uint2*)(src + c);      // 8B, rows 8B-aligned (80B stride)
    *(uint2*)(dst + c) = v;
  }
}

// ---- Lovász fill body (CE + optional KL via dense p3g + optional vote) ----
__device__ void fill_body(int bid0, const float* __restrict__ logits,
                          const int* __restrict__ lab, const int* __restrict__ vcnt,
                          int n, uint16_t* __restrict__ E,
                          float ceScale, float* __restrict__ lossAcc,
                          const float* __restrict__ p3g, float klScale) {
  int i = bid0 * 256 + threadIdx.x;
  float total = 0.f;
  if (i < n) {
    int lb;
    if (vcnt) {
      const int* crow = vcnt + (size_t)i * Cc;
      int best = crow[0], arg = 0;
      #pragma unroll
      for (int k = 1; k < Cc; k++) {
        int ck = crow[k];
        if (ck > best) { best = ck; arg = k; }   // first-max
      }
      lb = arg;
    } else {
      lb = lab[i];
    }
    const float* l = logits + (size_t)i * Cc;
    float m = l[0];
    #pragma unroll
    for (int c = 1; c < Cc; c++) m = fmaxf(m, l[c]);
    float ex[Cc]; float se = 0.f;
    #pragma unroll
    for (int c = 0; c < Cc; c++) { ex[c] = expf(l[c] - m); se += ex[c]; }
    float inv = 1.f / se;
    float lse = logf(se);
    total = -(l[lb] - m - lse) * ceScale;
    #pragma unroll
    for (int c = 0; c < Cc; c++) {
      float prob = ex[c] * inv;
      int fg = (c == lb) ? 1 : 0;
      float err = fg ? (1.f - prob) : prob;
      err = fmaxf(err, 0.f);
      uint32_t key = __float_as_uint(err) >> 17;     // < 8192
      E[(size_t)c * n + i] = (uint16_t)((key << 1) | (uint32_t)fg);
    }
    if (p3g) {
      const float* q = p3g + (size_t)i * Cc;         // dense pre-gathered
      float mq = q[0];
      #pragma unroll
      for (int c = 1; c < Cc; c++) mq = fmaxf(mq, q[c]);
      float sq = 0.f;
      #pragma unroll
      for (int c = 0; c < Cc; c++) sq += expf(q[c] - mq);
      float lsq = logf(sq);
      float kl = 0.f;
      #pragma unroll
      for (int c = 0; c < Cc; c++) {
        float lf = l[c] - m - lse;
        float pf = ex[c] * inv;
        float lq = q[c] - mq - lsq;
        kl += pf * (lf - lq);
      }
      total += kl * klScale;
    }
  }
  total = waveReduce(total);
  __shared__ float sh[4];
  int lane = threadIdx.x & 63, w = threadIdx.x >> 6;
  if (lane == 0) sh[w] = total;
  __syncthreads();
  if (threadIdx.x == 0) atomicAdd(lossAcc, sh[0] + sh[1] + sh[2] + sh[3]);
}

// ---- LDS-privatized histogram body (u64 global flush) ----
__device__ void hist_body(int bid0, const uint16_t* __restrict__ E, int n,
                          unsigned long long* __restrict__ H64, char* smem) {
  uint32_t* lcf = (uint32_t*)smem;                 // 8192 u32 = 32 KB
  int t = threadIdx.x;
  int cls = bid0 / NCH, ch = bid0 - cls * NCH;
  int CHsz = (n + NCH - 1) / NCH;
  int i0 = ch * CHsz;
  int i1 = min(n, i0 + CHsz);
  for (int b = t; b < NB; b += 256) lcf[b] = 0u;
  __syncthreads();
  const uint16_t* Ec = E + (size_t)cls * n;
  for (int i = i0 + t; i < i1; i += 256) {
    uint32_t p = Ec[i];
    atomicAdd(&lcf[p >> 1], 0x10000u | (p & 1u));    // count hi16, fg lo16
  }
  __syncthreads();
  unsigned long long* Hc = H64 + (size_t)cls * NB;
  for (int b = t; b < NB; b += 256) {
    uint32_t v = lcf[b];
    if (v)
      atomicAdd(&Hc[b], ((unsigned long long)(v >> 16) << 32) | (v & 0xFFFFu));
  }
}

// ---- dense-staged dual 64x64 GEMM + att + per-block BN partials ----
// LDS: sP(9216) sV(9216) sAtt(2048); sStat(4096) aliases sP after frag loads.
__device__ void gatt_body(int bid0, const uint16_t* __restrict__ pg,
                          const float* __restrict__ img,
                          const short* __restrict__ pc1, const float* __restrict__ c1b,
                          const short* __restrict__ pc2, const float* __restrict__ c2b,
                          const float* __restrict__ attEff,
                          uint16_t* __restrict__ y1, uint16_t* __restrict__ y2,
                          float* __restrict__ attw, float* __restrict__ partials,
                          char* smem) {
  short* sP = (short*)smem;                         // 64*72
  short* sV = (short*)(smem + 9216);                // 64*72
  float* sAtt  = (float*)(smem + 18432);            // 64*8
  float* sStat = (float*)smem;                      // aliases sP (after barrier)
  int t = threadIdx.x;
  int r0 = bid0 * 64;
  for (int i = t; i < 512; i += 256) {
    int r = i >> 3, q = i & 7;
    int gr = r0 + r;
    uint4 pv = make_uint4(0u, 0u, 0u, 0u);
    if (gr < NIMG) pv = *(const uint4*)(pg + (size_t)gr * 64 + q * 8);
    *(uint4*)(sP + r * 72 + q * 8) = pv;
  }
  for (int i = t; i < 1024; i += 256) {
    int r = i >> 4, q = i & 15;
    int gr = r0 + r;
    float4 vv = make_float4(0.f, 0.f, 0.f, 0.f);
    if (gr < NIMG) vv = *(const float4*)(img + (size_t)gr * 64 + q * 4);
    uint2 qv;
    qv.x = pk2(vv.x, vv.y); qv.y = pk2(vv.z, vv.w);
    *(uint2*)(sV + r * 72 + q * 4) = qv;
  }
  __syncthreads();
  {
    int r = t & 63, qq = t >> 6;
    const float* aP = attEff;
    const float* aV = attEff + 128;
    float l0 = 0.f, l1 = 0.f;
    for (int k = qq * 16; k < qq * 16 + 16; k += 4) {
      uint2 up = *(const uint2*)(sP + r * 72 + k);
      uint2 uv = *(const uint2*)(sV + r * 72 + k);
      float p0 = bf2f(up.x & 0xffff), p1 = bf2f(up.x >> 16);
      float p2 = bf2f(up.y & 0xffff), p3 = bf2f(up.y >> 16);
      float v0 = bf2f(uv.x & 0xffff), v1 = bf2f(uv.x >> 16);
      float v2 = bf2f(uv.y & 0xffff), v3 = bf2f(uv.y >> 16);
      float4 wa = *(const float4*)(aP + 2 * k);
      float4 wb = *(const float4*)(aP + 2 * k + 4);
      l0 += p0 * wa.x + p1 * wa.z + p2 * wb.x + p3 * wb.z;
      l1 += p0 * wa.y + p1 * wa.w + p2 * wb.y + p3 * wb.w;
      float4 ua = *(const float4*)(aV + 2 * k);
      float4 ub = *(const float4*)(aV + 2 * k + 4);
      l0 += v0 * ua.x + v1 * ua.z + v2 * ub.x + v3 * ub.z;
      l1 += v0 * ua.y + v1 * ua.w + v2 * ub.y + v3 * ub.w;
    }
    sAtt[r * 8 + qq * 2] = l0;
    sAtt[r * 8 + qq * 2 + 1] = l1;
  }
  const int lane = t & 63, w = t >> 6;
  const int m = lane & 15, quad = lane >> 4;
  const int rowA = 16 * w + m;
  bf16x8 ap[2], av[2];
  #pragma unroll
  for (int kt = 0; kt < 2; kt++) {
    ap[kt] = *(const bf16x8*)(sP + rowA * 72 + kt * 32 + quad * 8);
    av[kt] = *(const bf16x8*)(sV + rowA * 72 + kt * 32 + quad * 8);
  }
  __syncthreads();                 // all sP reads done before sStat aliases it
  const bf16x8* b1 = (const bf16x8*)pc1;
  const bf16x8* b2 = (const bf16x8*)pc2;
  #pragma unroll
  for (int nt = 0; nt < 4; nt++) {
    int col = nt * 16 + m;
    f32x4 c1 = {0.f, 0.f, 0.f, 0.f}, c2 = {0.f, 0.f, 0.f, 0.f};
    #pragma unroll
    for (int kt = 0; kt < 2; kt++) {
      c1 = __builtin_amdgcn_mfma_f32_16x16x32_bf16(ap[kt], b1[(kt * 4 + nt) * 64 + lane], c1, 0, 0, 0);
      c2 = __builtin_amdgcn_mfma_f32_16x16x32_bf16(av[kt], b2[(kt * 4 + nt) * 64 + lane], c2, 0, 0, 0);
    }
    float bb1 = c1b[col], bb2 = c2b[col];
    float s1 = 0.f, q1 = 0.f, s2 = 0.f, q2 = 0.f;
    #pragma unroll
    for (int reg = 0; reg < 4; reg++) {
      int gr = r0 + 16 * w + quad * 4 + reg;
      if (gr < NIMG) {
        float v1 = c1[reg] + bb1, v2 = c2[reg] + bb2;
        y1[(size_t)gr * 64 + col] = (uint16_t)f2bf(v1);
        y2[(size_t)gr * 64 + col] = (uint16_t)f2bf(v2);
        s1 += v1; q1 = fmaf(v1, v1, q1);
        s2 += v2; q2 = fmaf(v2, v2, q2);
      }
    }
    s1 += __shfl_down(s1, 32); s1 += __shfl_down(s1, 16);
    q1 += __shfl_down(q1, 32); q1 += __shfl_down(q1, 16);
    s2 += __shfl_down(s2, 32); s2 += __shfl_down(s2, 16);
    q2 += __shfl_down(q2, 32); q2 += __shfl_down(q2, 16);
    if (lane < 16) {
      float* base = sStat + (w * 4 + nt) * 64 + lane;
      base[0]  = s1;
      base[16] = q1;
      base[32] = s2;
      base[48] = q2;
    }
  }
  __syncthreads();
  {
    int kind = t >> 6, col = t & 63;
    int nt = col >> 4, mm = col & 15;
    float v = 0.f;
    #pragma unroll
    for (int ww = 0; ww < 4; ww++)
      v += sStat[(ww * 4 + nt) * 64 + kind * 16 + mm];
    partials[(size_t)bid0 * 256 + kind * 64 + col] = v;
  }
  if (t < 64) {
    int gr = r0 + t;
    if (gr < NIMG) {
      float l0 = attEff[256] + sAtt[t * 8] + sAtt[t * 8 + 2] + sAtt[t * 8 + 4] + sAtt[t * 8 + 6];
      float l1 = attEff[257] + sAtt[t * 8 + 1] + sAtt[t * 8 + 3] + sAtt[t * 8 + 5] + sAtt[t * 8 + 7];
      attw[gr * 2]     = 1.f / (1.f + expf(-l0));
      attw[gr * 2 + 1] = 1.f / (1.f + expf(-l1));
    }
  }
}

// ---- fuse (BN from red64, inline) -> feats + fuse-MLP (global fusepred) ----
// LDS: buf(17408, sSum/sXb/sH overlay) + sBn(1024) = 18432.
__device__ void fusemlp_body(int bid0,
    const uint16_t* __restrict__ y1, const uint16_t* __restrict__ y2,
    const float* __restrict__ attw, const float* __restrict__ red64,
    const float* __restrict__ g1, const float* __restrict__ be1,
    const float* __restrict__ g2, const float* __restrict__ be2,
    uint16_t* __restrict__ feats, int s64,
    const short* __restrict__ pw1, const float* __restrict__ B1,
    const short* __restrict__ pw2, const float* __restrict__ B2,
    float* __restrict__ Out, char* smem) {
  short* buf = (short*)smem;                    // sSum -> sXb -> sH overlay
  float* sBn = (float*)(smem + 17408);          // 256 floats
  int t = threadIdx.x, r0 = bid0 * 64;
  float acc = 0.f;
  #pragma unroll 8
  for (int b = 0; b < 64; b++) acc += red64[b * 256 + t];
  float* sSum = (float*)buf;                    // scratch
  sSum[t] = acc;
  __syncthreads();
  if (t < 64) {
    float nn = (float)NIMG;
    float mu1 = sSum[t] / nn;
    float var1 = sSum[64 + t] / nn - mu1 * mu1;
    float a1 = g1[t] / sqrtf(var1 + BN_EPS);
    sBn[t] = a1; sBn[64 + t] = be1[t] - mu1 * a1;
    float mu2 = sSum[128 + t] / nn;
    float var2 = sSum[192 + t] / nn - mu2 * mu2;
    float a2 = g2[t] / sqrtf(var2 + BN_EPS);
    sBn[128 + t] = a2; sBn[192 + t] = be2[t] - mu2 * a2;
  }
  __syncthreads();
  for (int i = t; i < 1024; i += 256) {
    int r = i >> 4, q = i & 15;
    int gr = r0 + r;
    uint2 zp = make_uint2(0u, 0u);
    if (gr < NIMG) {
      float4 a1 = *(const float4*)(sBn + q * 4);
      float4 c1 = *(const float4*)(sBn + 64 + q * 4);
      float4 a2 = *(const float4*)(sBn + 128 + q * 4);
      float4 c2 = *(const float4*)(sBn + 192 + q * 4);
      uint2 u1 = *(const uint2*)(y1 + (size_t)gr * 64 + q * 4);
      uint2 u2 = *(const uint2*)(y2 + (size_t)gr * 64 + q * 4);
      float w0 = attw[gr * 2], w1 = attw[gr * 2 + 1];
      float zx = fmaxf(fmaf(bf2f(u1.x & 0xffff), a1.x, c1.x), 0.f) * w0
               + fmaxf(fmaf(bf2f(u2.x & 0xffff), a2.x, c2.x), 0.f) * w1;
      float zy = fmaxf(fmaf(bf2f(u1.x >> 16),   a1.y, c1.y), 0.f) * w0
               + fmaxf(fmaf(bf2f(u2.x >> 16),   a2.y, c2.y), 0.f) * w1;
      float zz = fmaxf(fmaf(bf2f(u1.y & 0xffff), a1.z, c1.z), 0.f) * w0
               + fmaxf(fmaf(bf2f(u2.y & 0xffff), a2.z, c2.z), 0.f) * w1;
      float zw = fmaxf(fmaf(bf2f(u1.y >> 16),   a1.w, c1.w), 0.f) * w0
               + fmaxf(fmaf(bf2f(u2.y >> 16),   a2.w, c2.w), 0.f) * w1;
      zp.x = pk2(zx, zy); zp.y = pk2(zz, zw);
      *(uint2*)(feats + (size_t)gr * 128 + s64 + q * 4) = zp;
    }
    *(uint2*)(buf + r * 72 + q * 4) = zp;
  }
  __syncthreads();
  mfma_mlp_core<64, false>(buf, buf, nullptr, r0, NIMG, pw1, B1, pw2, B2, Out);
}

// ===================== wrapper kernels (block-range bundles) ===============
// D2: gatt(s0) + gatt(s1) + pred3d MLP x2 + counts x2
__global__ void __launch_bounds__(256)
k_mega2(const float* __restrict__ pf0, const float* __restrict__ pf1,
        const uint16_t* __restrict__ pg0, const uint16_t* __restrict__ pg1,
        const float* __restrict__ if0, const float* __restrict__ if1,
        const short* pc1w0, const short* pc1w1, const short* pc2w0, const short* pc2w1,
        const float* c1b, const float* c2b, const float* attEffs,
        uint16_t* y1a, uint16_t* y2a, uint16_t* y1b, uint16_t* y2b,
        float* attw0, float* attw1, float* partials0, float* partials1,
        const short* pw3a0, const float* b3a, const short* pw3b0, const float* b3b,
        const short* pw3a1, const short* pw3b1,
        float* pred3d0, float* pred3d1,
        const int* __restrict__ ci0, const int* __restrict__ ci1,
        const int* __restrict__ labels,
        int* __restrict__ counts0, int* __restrict__ counts1) {
  __shared__ char smem[20480];
  int bid = blockIdx.x;
  if (bid < NBLK_GA) {
    gatt_body(bid, pg0, if0, pc1w0, c1b, pc2w0, c2b, attEffs,
              y1a, y2a, attw0, partials0, smem);
    return;
  }
  bid -= NBLK_GA;
  if (bid < NBLK_GA) {
    gatt_body(bid, pg1, if1, pc1w1, c1b + 64, pc2w1, c2b + 64, attEffs + 320,
              y1b, y2b, attw1, partials1, smem);
    return;
  }
  bid -= NBLK_GA;
  if (bid < NBLK_MLP) { mlp64_body(bid, pf0, pw3a0, b3a, pw3b0, b3b, pred3d0, NV, smem); return; }
  bid -= NBLK_MLP;
  if (bid < NBLK_MLP) { mlp64_body(bid, pf1, pw3a1, b3a + 128, pw3b1, b3b + Cc, pred3d1, NV, smem); return; }
  bid -= NBLK_MLP;
  if (bid < NBLK_CNT) { cnt_body(bid, ci0, labels, counts0); return; }
  cnt_body(bid - NBLK_CNT, ci1, labels, counts1);
}

// D3: colred x2 + pred3d-gather (fast; clears fusemlp's only dependency)
__global__ void __launch_bounds__(256)
k_colred_p3g(const float* partials0, float* red64_0,
             const float* partials1, float* red64_1,
             const float* __restrict__ pred3d0, const float* __restrict__ pred3d1,
             const int* __restrict__ idx0, const int* __restrict__ idx1,
             float* __restrict__ p3g0, float* __restrict__ p3g1) {
  int bid = blockIdx.x;
  if (bid < 64) { colred_body(bid, partials0, red64_0); return; }
  bid -= 64;
  if (bid < 64) { colred_body(bid, partials1, red64_1); return; }
  p3gath_body(bid - 64, pred3d0, pred3d1, idx0, idx1, p3g0, p3g1);
}

// D4: fusemlp x2 (BN inline) + fill_NV x2 (vote inline)
__global__ void __launch_bounds__(256)
k_fuse2_fill2(const uint16_t* y1a, const uint16_t* y2a, const float* attw0, const float* red64_0,
              const uint16_t* y1b, const uint16_t* y2b, const float* attw1, const float* red64_1,
              const float* bn1g, const float* bn1b, const float* bn2g, const float* bn2b,
              uint16_t* feats,
              const short* pwfa0, const float* bfa, const short* pwfb0, const float* bfb,
              const short* pwfa1, const short* pwfb1,
              float* fusepred0, float* fusepred1,
              const float* __restrict__ pred3d0, const int* __restrict__ counts0,
              uint16_t* __restrict__ E0,
              const float* __restrict__ pred3d1, const int* __restrict__ counts1,
              uint16_t* __restrict__ E1,
              float ceNV, float* lossAcc) {
  __shared__ char smem[18432];
  int bid = blockIdx.x;
  if (bid < NBLK_GA) {
    fusemlp_body(bid, y1a, y2a, attw0, red64_0, bn1g, bn1b, bn2g, bn2b, feats, 0,
                 pwfa0, bfa, pwfb0, bfb, fusepred0, smem);
    return;
  }
  bid -= NBLK_GA;
  if (bid < NBLK_GA) {
    fusemlp_body(bid, y1b, y2b, attw1, red64_1, bn1g + 64, bn1b + 64, bn2g + 64, bn2b + 64,
                 feats, 64, pwfa1, bfa + 128, pwfb1, bfb + Cc, fusepred1, smem);
    return;
  }
  bid -= NBLK_GA;
  if (bid < NBLK_FILL_NV) {
    fill_body(bid, pred3d0, nullptr, counts0, NV, E0, ceNV, lossAcc, nullptr, 0.f);
    return;
  }
  fill_body(bid - NBLK_FILL_NV, pred3d1, nullptr, counts1, NV, E1, ceNV, lossAcc, nullptr, 0.f);
}

// D5: final MLP (fused fill4 -> E2) + fill1 + fill3 + hist0 + hist2
__global__ void __launch_bounds__(256)
k_finx2(const uint16_t* __restrict__ feats,
        const short* pcl1, const float* clb1, const short* pcl2, const float* clb2,
        const int* __restrict__ img_label, uint16_t* E2, float ce4, float* lossAcc,
        const float* fusepred0, const float* p3g0, uint16_t* E3,
        const float* fusepred1, const float* p3g1, uint16_t* E4,
        float ce, float kl,
        const uint16_t* __restrict__ E0, unsigned long long* H0,
        const uint16_t* __restrict__ E1, unsigned long long* H2) {
  __shared__ char smem[32768];
  int bid = blockIdx.x;
  if (bid < NBLK_GA) {
    mlp128_loss_body(bid, feats, pcl1, clb1, pcl2, clb2, img_label, E2, ce4, lossAcc, smem);
    return;
  }
  bid -= NBLK_GA;
  if (bid < NBLK_FILL_NI) {
    fill_body(bid, fusepred0, img_label, nullptr, NIMG, E3, ce, lossAcc, p3g0, kl);
    return;
  }
  bid -= NBLK_FILL_NI;
  if (bid < NBLK_FILL_NI) {
    fill_body(bid, fusepred1, img_label, nullptr, NIMG, E4, ce, lossAcc, p3g1, kl);
    return;
  }
  bid -= NBLK_FILL_NI;
  if (bid < NBLK_HIST) { hist_body(bid, E0, NV, H0, smem); return; }
  hist_body(bid - NBLK_HIST, E1, NV, H2, smem);
}

// D6: hist1(E3) + hist3(E4) + hist4(E2) + scan0 + scan2
__global__ void __launch_bounds__(256)
k_hist3_scan2(const uint16_t* __restrict__ E3, unsigned long long* H1,
              const uint16_t* __restrict__ E4, unsigned long long* H3,
              const uint16_t* __restrict__ E2, unsigned long long* H4,
              const unsigned long long* H0, const unsigned long long* H2s,
              float* lossesC5, int* gts5) {
  __shared__ char smem[32768];
  int bid = blockIdx.x;
  if (bid < NBLK_HIST) { hist_body(bid, E3, NIMG, H1, smem); return; }
  bid -= NBLK_HIST;
  if (bid < NBLK_HIST) { hist_body(bid, E4, NIMG, H3, smem); return; }
  bid -= NBLK_HIST;
  if (bid < NBLK_HIST) { hist_body(bid, E2, NIMG, H4, smem); return; }
  bid -= NBLK_HIST;
  if (bid < Cc) { scanbin_body(H0, NV, 0, lossesC5, gts5, bid); return; }
  scanbin_body(H2s, NV, 2, lossesC5, gts5, bid - Cc);
}

// D7: scan1 + scan3 + scan4
__global__ void __launch_bounds__(256)
k_scan3(const unsigned long long* H1, const unsigned long long* H3,
        const unsigned long long* H4,
        float* lossesC5, int* gts5) {
  int bid = blockIdx.x;
  if (bid < Cc) { scanbin_body(H1, NIMG, 1, lossesC5, gts5, bid); return; }
  bid -= Cc;
  if (bid < Cc) { scanbin_body(H3, NIMG, 3, lossesC5, gts5, bid); return; }
  scanbin_body(H4, NIMG, 4, lossesC5, gts5, bid - Cc);
}

// D8: fold 5 lovász combines + output
__global__ void k_final(const float* __restrict__ lossAcc,
                        const float* __restrict__ lossesC5, const int* __restrict__ gts5,
                        float* __restrict__ out) {
  const float coefs[5] = {1.0f, 0.5f, 1.0f, 0.5f, 1.0f};
  float loss = lossAcc[0];
  for (int call = 0; call < 5; call++) {
    float s = 0.f; int np = 0;
    for (int c = 0; c < Cc; c++)
      if (gts5[call * 32 + c] > 0) { s += lossesC5[call * 32 + c]; np++; }
    loss += coefs[call] * s / (float)(np > 0 ? np : 1);
  }
  out[0] = loss;
}

// ================= host-side driver =================
extern "C" void kernel_launch(void* const* d_in, const int* in_sizes, int n_in,
                              void* d_out, int out_size, void* d_ws, size_t ws_size,
                              hipStream_t stream) {
  const float* img_feat = (const float*)d_in[0];
  const float* pts_feat = (const float*)d_in[1];
  const int* coors_inv  = (const int*)d_in[2];
  const int* labels     = (const int*)d_in[3];
  const int* img_label  = (const int*)d_in[4];
  const int* p2img      = (const int*)d_in[5];
  const float* w3a = (const float*)d_in[6];
  const float* b3a = (const float*)d_in[7];
  const float* w3b = (const float*)d_in[8];
  const float* b3b = (const float*)d_in[9];
  const float* wfa = (const float*)d_in[10];
  const float* bfa = (const float*)d_in[11];
  const float* wfb = (const float*)d_in[12];
  const float* bfb = (const float*)d_in[13];
  const float* fc1w = (const float*)d_in[14];
  const float* fc1b = (const float*)d_in[15];
  const float* fc2w = (const float*)d_in[16];
  const float* fc2b = (const float*)d_in[17];
  const float* fc3w = (const float*)d_in[18];
  const float* fc3b = (const float*)d_in[19];
  const float* c1w  = (const float*)d_in[20];
  const float* c1b  = (const float*)d_in[21];
  const float* bn1g = (const float*)d_in[22];
  const float* bn1b = (const float*)d_in[23];
  const float* c2w  = (const float*)d_in[24];
  const float* c2b  = (const float*)d_in[25];
  const float* bn2g = (const float*)d_in[26];
  const float* bn2b = (const float*)d_in[27];
  const float* clw1 = (const float*)d_in[28];
  const float* clb1 = (const float*)d_in[29];
  const float* clw2 = (const float*)d_in[30];
  const float* clb2 = (const float*)d_in[31];
  (void)in_sizes; (void)n_in; (void)out_size; (void)ws_size;

  // ---- workspace layout ----
  char* ws = (char*)d_ws;
  size_t off = 0;
  auto alloc = [&](size_t bytes) { void* p = ws + off; off += (bytes + 255) & ~(size_t)255; return p; };
  uint16_t* feats = (uint16_t*)alloc((size_t)NIMG * 128 * 2);
  uint16_t* pgath = (uint16_t*)alloc((size_t)2 * NIMG * 64 * 2);  // dense gathered pts (bf16)
  float* pred3d0 = (float*)alloc((size_t)NV * Cc * 4);
  float* pred3d1 = (float*)alloc((size_t)NV * Cc * 4);
  float* p3g0 = (float*)alloc((size_t)NIMG * Cc * 4);             // dense gathered pred3d
  float* p3g1 = (float*)alloc((size_t)NIMG * Cc * 4);
  int* idx0 = (int*)alloc((size_t)NIMG * 4);
  int* idx1 = (int*)alloc((size_t)NIMG * 4);
  uint16_t* y1a = (uint16_t*)alloc((size_t)NIMG * Hh * 2);
  uint16_t* y2a = (uint16_t*)alloc((size_t)NIMG * Hh * 2);
  uint16_t* y1b = (uint16_t*)alloc((size_t)NIMG * Hh * 2);
  uint16_t* y2b = (uint16_t*)alloc((size_t)NIMG * Hh * 2);
  uint16_t* E0 = (uint16_t*)alloc((size_t)Cc * NV * 2);
  uint16_t* E1 = (uint16_t*)alloc((size_t)Cc * NV * 2);
  uint16_t* E2 = (uint16_t*)alloc((size_t)Cc * NIMG * 2);
  uint16_t* E3 = (uint16_t*)alloc((size_t)Cc * NIMG * 2);
  uint16_t* E4 = (uint16_t*)alloc((size_t)Cc * NIMG * 2);
  float* partials0 = (float*)alloc((size_t)NBLK_GA * 256 * 4);
  float* partials1 = (float*)alloc((size_t)NBLK_GA * 256 * 4);
  float* red64_0 = (float*)alloc(64 * 256 * 4);
  float* red64_1 = (float*)alloc(64 * 256 * 4);
  float* attw0 = (float*)alloc((size_t)NIMG * 2 * 4);
  float* attw1 = (float*)alloc((size_t)NIMG * 2 * 4);
  float* fusepred0 = (float*)alloc((size_t)NIMG * Cc * 4);
  float* fusepred1 = (float*)alloc((size_t)NIMG * Cc * 4);
  short* pwAll = (short*)alloc(86016 * 2);
  short* pw3a0 = pwAll,          * pw3a1 = pwAll + 8192;
  short* pwfa0 = pwAll + 16384,  * pwfa1 = pwAll + 24576;
  short* pw3b0 = pwAll + 32768,  * pw3b1 = pwAll + 36864;
  short* pwfb0 = pwAll + 40960,  * pwfb1 = pwAll + 45056;
  short* pcl1  = pwAll + 49152;
  short* pcl2  = pwAll + 65536;
  short* pc1w0 = pwAll + 69632,  * pc1w1 = pwAll + 73728;
  short* pc2w0 = pwAll + 77824,  * pc2w1 = pwAll + 81920;
  float* attEffs = (float*)alloc(2 * 320 * 4);
  // ---- contiguous zero region: stats(4096B) + 5x u64 hist + counts0/1 ----
  // (4096B stats region fixes the former gts5->Hc(0) overlap)
  size_t zsize = 4096 + (size_t)5 * Cc * NB * 8 + (size_t)2 * NV * Cc * 4;
  char* zbase = (char*)alloc(zsize);
  float* lossAcc  = (float*)zbase;                 // [0]
  float* lossesC5 = (float*)zbase + 32;            // 5*32 floats
  int*   gts5     = (int*)((float*)zbase + 192);   // 5*32 ints (ends at 1408 < 4096)
  unsigned long long* Hbase = (unsigned long long*)(zbase + 4096);
  auto Hc = [&](int call) { return Hbase + (size_t)call * Cc * NB; };
  int* counts0 = (int*)(zbase + 4096 + (size_t)5 * Cc * NB * 8);
  int* counts1 = counts0 + (size_t)NV * Cc;
  int zq = (int)(zsize / 16);

  const float kl = 0.025f / ((float)NIMG * Cc);
  const float* pf0 = pts_feat;
  const float* pf1 = pts_feat + (size_t)NV * Hh;
  const float* if0 = img_feat;
  const float* if1 = img_feat + (size_t)NIMG * Hh;
  const int* ci0 = coors_inv;
  const int* ci1 = coors_inv + NPT;
  uint16_t* pg0 = pgath;
  uint16_t* pg1 = pgath + (size_t)NIMG * 64;

  // D1: pack weights + zero ws region + fused idx/pts-gather
  PackArgs pa;
  pa.d[0]  = {w3a,        pw3a0, 64, 128, 8};
  pa.d[1]  = {w3a + 8192, pw3a1, 64, 128, 8};
  pa.d[2]  = {wfa,        pwfa0, 64, 128, 8};
  pa.d[3]  = {wfa + 8192, pwfa1, 64, 128, 8};
  pa.d[4]  = {w3b,        pw3b0, 128, 20, 2};
  pa.d[5]  = {w3b + 2560, pw3b1, 128, 20, 2};
  pa.d[6]  = {wfb,        pwfb0, 128, 20, 2};
  pa.d[7]  = {wfb + 2560, pwfb1, 128, 20, 2};
  pa.d[8]  = {clw1,       pcl1, 128, 128, 8};
  pa.d[9]  = {clw2,       pcl2, 128, 20, 2};
  pa.d[10] = {c1w,        pc1w0, 64, 64, 4};
  pa.d[11] = {c1w + 4096, pc1w1, 64, 64, 4};
  pa.d[12] = {c2w,        pc2w0, 64, 64, 4};
  pa.d[13] = {c2w + 4096, pc2w1, 64, 64, 4};
  k_pack_zero<<<384 + NBLK_GATH, 256, 0, stream>>>(
      pa, fc1w, fc1b, fc2w, fc2b, fc3w, fc3b, attEffs,
      (uint4*)zbase, zq, ci0, ci1, p2img, idx0, idx1, pts_feat, pgath);

  // D2: gatt x2 (dense-staged) + pred3d MLP x2 + counts x2
  k_mega2<<<2 * NBLK_GA + 2 * NBLK_MLP + 2 * NBLK_CNT, 256, 0, stream>>>(
      pf0, pf1, pg0, pg1, if0, if1,
      pc1w0, pc1w1, pc2w0, pc2w1, c1b, c2b, attEffs,
      y1a, y2a, y1b, y2b, attw0, attw1, partials0, partials1,
      pw3a0, b3a, pw3b0, b3b, pw3a1, pw3b1, pred3d0, pred3d1,
      ci0, ci1, labels, counts0, counts1);

  // D3: colred x2 + pred3d-gather (fast critical-path stage)
  k_colred_p3g<<<128 + NBLK_P3G, 256, 0, stream>>>(
      partials0, red64_0, partials1, red64_1,
      pred3d0, pred3d1, idx0, idx1, p3g0, p3g1);

  // D4: fusemlp x2 (BN inline) + fill_NV x2 (vote inline)
  k_fuse2_fill2<<<2 * NBLK_GA + 2 * NBLK_FILL_NV, 256, 0, stream>>>(
      y1a, y2a, attw0, red64_0, y1b, y2b, attw1, red64_1,
      bn1g, bn1b, bn2g, bn2b, feats,
      pwfa0, bfa, pwfb0, bfb, pwfa1, pwfb1, fusepred0, fusepred1,
      pred3d0, counts0, E0, pred3d1, counts1, E1,
      1.0f / NV, lossAcc);

  // D5: final MLP (+fused fill4 -> E2) + fill1 + fill3 + hist0 + hist2
  k_finx2<<<NBLK_GA + 2 * NBLK_FILL_NI + 2 * NBLK_HIST, 256, 0, stream>>>(
      feats, pcl1, clb1, pcl2, clb2,
      img_label, E2, 1.0f / NIMG, lossAcc,
      fusepred0, p3g0, E3,
      fusepred1, p3g1, E4,
      0.5f / NIMG, kl,
      E0, Hc(0), E1, Hc(2));

  // D6: hist1 + hist3 + hist4 + scan0 + scan2
  k_hist3_scan2<<<3 * NBLK_HIST + 2 * Cc, 256, 0, stream>>>(
      E3, Hc(1), E4, Hc(3), E2, Hc(4),
      Hc(0), Hc(2), lossesC5, gts5);

  // D7: scan1 + scan3 + scan4
  k_scan3<<<3 * Cc, 256, 0, stream>>>(Hc(1), Hc(3), Hc(4), lossesC5, gts5);

  // D8: fold + output
  k_final<<<1, 1, 0, stream>>>(lossAcc, lossesC5, gts5, (float*)d_out);
}